// Round 1
// baseline (3047.916 us; speedup 1.0000x reference)
//
#include <hip/hip_runtime.h>
#include <cstdint>
#include <cstddef>

#define B_    8
#define L_    256
#define DM_   1024
#define DI_   2048
#define N_    16
#define K_    4
#define NL_   4
#define DTR_  128
#define P_    97
#define XPD_  160   // DTR + 2N
#define CHUNK_ 32
#define NC_   8     // L / CHUNK

// ---------------------------------------------------------------------------
// Embedding: h[b,l,:] = tok_emb[tokens[b,l],:] + pos_emb[l,:]
// ---------------------------------------------------------------------------
__global__ __launch_bounds__(256)
void embed_k(const int* __restrict__ tokens, const float* __restrict__ te,
             const float* __restrict__ pe, float* __restrict__ h)
{
    int idx = blockIdx.x * 256 + threadIdx.x;   // over B*L*DM
    int m  = idx & (DM_ - 1);
    int bl = idx >> 10;
    int l  = bl & (L_ - 1);
    int tok = tokens[bl];
    h[idx] = te[tok * DM_ + m] + pe[l * DM_ + m];
}

// ---------------------------------------------------------------------------
// LayerNorm over DM=1024. One block per row. rstep/rbase allow selecting
// strided rows (final LN on last token only).
// ---------------------------------------------------------------------------
__global__ __launch_bounds__(256)
void layernorm_k(const float* __restrict__ in, const float* __restrict__ w,
                 const float* __restrict__ b, float* __restrict__ out,
                 int rstep, int rbase)
{
    __shared__ float red[8];
    int row_in = blockIdx.x * rstep + rbase;
    const float* p = in + (size_t)row_in * DM_;
    int tid = threadIdx.x;
    float4 x = *(const float4*)(p + tid * 4);
    float s  = x.x + x.y + x.z + x.w;
    float s2 = x.x * x.x + x.y * x.y + x.z * x.z + x.w * x.w;
    #pragma unroll
    for (int o = 32; o > 0; o >>= 1) {
        s  += __shfl_down(s, o);
        s2 += __shfl_down(s2, o);
    }
    if ((tid & 63) == 0) { red[tid >> 6] = s; red[4 + (tid >> 6)] = s2; }
    __syncthreads();
    float st  = red[0] + red[1] + red[2] + red[3];
    float s2t = red[4] + red[5] + red[6] + red[7];
    float m   = st * (1.f / DM_);
    float var = s2t * (1.f / DM_) - m * m;
    float rs  = rsqrtf(var + 1e-5f);
    float4 wv = *(const float4*)(w + tid * 4);
    float4 bv = *(const float4*)(b + tid * 4);
    float4 o4;
    o4.x = (x.x - m) * rs * wv.x + bv.x;
    o4.y = (x.y - m) * rs * wv.y + bv.y;
    o4.z = (x.z - m) * rs * wv.z + bv.z;
    o4.w = (x.w - m) * rs * wv.w + bv.w;
    *(float4*)(out + (size_t)blockIdx.x * DM_ + tid * 4) = o4;
}

// ---------------------------------------------------------------------------
// Generic fp32 GEMM: C[m,n] = dot(A[m,:K], Bw[n,:K]) (+bias) (softplus) (+=C)
// 64x64 tile, 256 threads, 4x4 microtile, LDS in [k][row] layout (pad 68 so
// float4 reads stay 16B-aligned; k-stride 68*4=272B -> <=2-way bank alias).
// ---------------------------------------------------------------------------
template<bool BIAS, bool SOFTPLUS, bool RES, bool NBOUND>
__global__ __launch_bounds__(256)
void gemm_nt(const float* __restrict__ A, int lda,
             const float* __restrict__ Bw, int ldb,
             float* __restrict__ C, int ldc,
             const float* __restrict__ bias, int N, int Kdim)
{
    __shared__ float As[16][68];
    __shared__ float Bs[16][68];
    const int tid = threadIdx.x;
    const int tx = tid & 15, ty = tid >> 4;
    const int mbase = blockIdx.y * 64;
    const int nbase = blockIdx.x * 64;
    const int kk = tid & 15;   // k within tile (loader)
    const int r0 = tid >> 4;   // row group (loader)
    float acc[4][4] = {};

    for (int k0 = 0; k0 < Kdim; k0 += 16) {
        #pragma unroll
        for (int i = 0; i < 4; ++i) {
            int row = r0 + i * 16;
            As[kk][row] = A[(size_t)(mbase + row) * lda + k0 + kk];
            float v = 0.f;
            if (!NBOUND || (nbase + row) < N)
                v = Bw[(size_t)(nbase + row) * ldb + k0 + kk];
            Bs[kk][row] = v;
        }
        __syncthreads();
        #pragma unroll
        for (int k = 0; k < 16; ++k) {
            const float4 av = *(const float4*)&As[k][ty * 4];
            const float4 bv = *(const float4*)&Bs[k][tx * 4];
            const float aa[4] = {av.x, av.y, av.z, av.w};
            const float bb[4] = {bv.x, bv.y, bv.z, bv.w};
            #pragma unroll
            for (int i = 0; i < 4; ++i)
                #pragma unroll
                for (int j = 0; j < 4; ++j)
                    acc[i][j] = fmaf(aa[i], bb[j], acc[i][j]);
        }
        __syncthreads();
    }

    #pragma unroll
    for (int i = 0; i < 4; ++i) {
        int row = mbase + ty * 4 + i;
        if (NBOUND) {
            for (int j = 0; j < 4; ++j) {
                int col = nbase + tx * 4 + j;
                if (col < N) {
                    float v = acc[i][j];
                    if (BIAS) v += bias[col];
                    if (SOFTPLUS) v = (v > 20.f) ? v : log1pf(__expf(v));
                    size_t off = (size_t)row * ldc + col;
                    if (RES) C[off] += v; else C[off] = v;
                }
            }
        } else {
            float vv[4];
            #pragma unroll
            for (int j = 0; j < 4; ++j) {
                float v = acc[i][j];
                if (BIAS) v += bias[nbase + tx * 4 + j];
                if (SOFTPLUS) v = (v > 20.f) ? v : log1pf(__expf(v));
                vv[j] = v;
            }
            size_t off = (size_t)row * ldc + nbase + tx * 4;
            if (RES) {
                float4 old = *(const float4*)&C[off];
                vv[0] += old.x; vv[1] += old.y; vv[2] += old.z; vv[3] += old.w;
            }
            *(float4*)&C[off] = make_float4(vv[0], vv[1], vv[2], vv[3]);
        }
    }
}

// ---------------------------------------------------------------------------
// Causal depthwise conv (K=4) over L + SiLU. Input = xz[..., :DI].
// ---------------------------------------------------------------------------
__global__ __launch_bounds__(256)
void conv_silu(const float* __restrict__ xz, const float* __restrict__ cw,
               const float* __restrict__ cb, float* __restrict__ xb)
{
    int idx = blockIdx.x * 256 + threadIdx.x;   // over B*L*DI
    int d  = idx & (DI_ - 1);
    int bl = idx >> 11;
    int l  = bl & (L_ - 1);
    float s = cb[d];
    #pragma unroll
    for (int k = 0; k < 4; ++k) {
        int lk = l + k - 3;
        if (lk >= 0)
            s += cw[d * 4 + k] * xz[(size_t)(bl - l + lk) * (2 * DI_) + d];
    }
    xb[idx] = s / (1.f + __expf(-s));   // silu
}

// ---------------------------------------------------------------------------
// SSM chunked scan. Chunk layout for P/S/hstart: [b][c][n][d] (d coalesced).
// pass1: per (b,c,d): local scan from 0 -> P (decay product), S (final state)
// ---------------------------------------------------------------------------
__global__ __launch_bounds__(256)
void ssm_pass1(const float* __restrict__ xb, const float* __restrict__ dlt,
               const float* __restrict__ xp, const float* __restrict__ Alog,
               float* __restrict__ Pc, float* __restrict__ Sc)
{
    int blk = blockIdx.x;
    int dgrp = blk & 7, c = (blk >> 3) & 7, b = blk >> 6;
    int d = (dgrp << 8) + threadIdx.x;
    __shared__ float Bsh[CHUNK_][N_];
    for (int i = threadIdx.x; i < CHUNK_ * N_; i += 256) {
        int t = i >> 4, n = i & 15;
        Bsh[t][n] = xp[(size_t)(b * L_ + c * CHUNK_ + t) * XPD_ + DTR_ + n];
    }
    __syncthreads();
    float a[N_], hn[N_], Pn[N_];
    #pragma unroll
    for (int n = 0; n < N_; ++n) {
        a[n] = -__expf(Alog[d * N_ + n]);
        hn[n] = 0.f; Pn[n] = 1.f;
    }
    for (int t = 0; t < CHUNK_; ++t) {
        size_t off = (size_t)(b * L_ + c * CHUNK_ + t) * DI_ + d;
        float dt = dlt[off], xv = xb[off];
        float dx = dt * xv;
        #pragma unroll
        for (int n = 0; n < N_; ++n) {
            float dA = __expf(dt * a[n]);
            hn[n] = dA * hn[n] + dx * Bsh[t][n];
            Pn[n] *= dA;
        }
    }
    #pragma unroll
    for (int n = 0; n < N_; ++n) {
        size_t o = ((size_t)((b * NC_ + c) * N_ + n)) * DI_ + d;
        Pc[o] = Pn[n]; Sc[o] = hn[n];
    }
}

// Sequential scan over the 8 chunk boundaries (cheap, fully parallel in b,n,d)
__global__ __launch_bounds__(256)
void ssm_scan(const float* __restrict__ Pc, const float* __restrict__ Sc,
              float* __restrict__ hstart)
{
    int idx = blockIdx.x * 256 + threadIdx.x;   // over B*N*DI
    int d = idx & (DI_ - 1);
    int bn = idx >> 11;
    int n = bn & 15, b = bn >> 4;
    float h = 0.f;
    for (int c = 0; c < NC_; ++c) {
        size_t o = ((size_t)((b * NC_ + c) * N_ + n)) * DI_ + d;
        hstart[o] = h;
        h = Pc[o] * h + Sc[o];
    }
}

// pass2: re-run chunk from hstart, emit y = (C.h + x*D) * silu(z)
__global__ __launch_bounds__(256)
void ssm_pass2(const float* __restrict__ xb, const float* __restrict__ dlt,
               const float* __restrict__ xp, const float* __restrict__ Alog,
               const float* __restrict__ Dp, const float* __restrict__ xz,
               const float* __restrict__ hstart, float* __restrict__ yout)
{
    int blk = blockIdx.x;
    int dgrp = blk & 7, c = (blk >> 3) & 7, b = blk >> 6;
    int d = (dgrp << 8) + threadIdx.x;
    __shared__ float Bsh[CHUNK_][N_], Csh[CHUNK_][N_];
    for (int i = threadIdx.x; i < CHUNK_ * 2 * N_; i += 256) {
        int t = i >> 5, j = i & 31;
        float v = xp[(size_t)(b * L_ + c * CHUNK_ + t) * XPD_ + DTR_ + j];
        if (j < 16) Bsh[t][j] = v; else Csh[t][j - 16] = v;
    }
    __syncthreads();
    float a[N_], hn[N_];
    #pragma unroll
    for (int n = 0; n < N_; ++n) {
        a[n] = -__expf(Alog[d * N_ + n]);
        hn[n] = hstart[((size_t)((b * NC_ + c) * N_ + n)) * DI_ + d];
    }
    float dpv = Dp[d];
    for (int t = 0; t < CHUNK_; ++t) {
        int l = c * CHUNK_ + t;
        size_t off = (size_t)(b * L_ + l) * DI_ + d;
        float dt = dlt[off], xv = xb[off];
        float dx = dt * xv;
        float yv = 0.f;
        #pragma unroll
        for (int n = 0; n < N_; ++n) {
            float dA = __expf(dt * a[n]);
            hn[n] = dA * hn[n] + dx * Bsh[t][n];
            yv += hn[n] * Csh[t][n];
        }
        yv += xv * dpv;
        float z = xz[(size_t)(b * L_ + l) * (2 * DI_) + DI_ + d];
        yout[off] = yv * z / (1.f + __expf(-z));
    }
}

// ---------------------------------------------------------------------------
// Head: out[b,p] = dot(hln[b,:], head_w[p,:])  (8x97, one block per output)
// ---------------------------------------------------------------------------
__global__ __launch_bounds__(256)
void head_k(const float* __restrict__ hln, const float* __restrict__ hw,
            float* __restrict__ out)
{
    __shared__ float red[4];
    int b = blockIdx.x / P_;
    int p = blockIdx.x % P_;
    int tid = threadIdx.x;
    const float* av = hln + (size_t)b * DM_;
    const float* wv = hw + (size_t)p * DM_;
    float4 xa = *(const float4*)(av + tid * 4);
    float4 xw = *(const float4*)(wv + tid * 4);
    float s = xa.x * xw.x + xa.y * xw.y + xa.z * xw.z + xa.w * xw.w;
    #pragma unroll
    for (int o = 32; o > 0; o >>= 1) s += __shfl_down(s, o);
    if ((tid & 63) == 0) red[tid >> 6] = s;
    __syncthreads();
    if (tid == 0) out[blockIdx.x] = red[0] + red[1] + red[2] + red[3];
}

// ---------------------------------------------------------------------------
extern "C" void kernel_launch(void* const* d_in, const int* in_sizes, int n_in,
                              void* d_out, int out_size, void* d_ws, size_t ws_size,
                              hipStream_t stream)
{
    const int*   tokens     = (const int*)  d_in[0];
    const float* tok_emb    = (const float*)d_in[1];
    const float* pos_emb    = (const float*)d_in[2];
    const float* ln_w       = (const float*)d_in[3];
    const float* ln_b       = (const float*)d_in[4];
    const float* in_proj_w  = (const float*)d_in[5];
    const float* conv_w     = (const float*)d_in[6];
    const float* conv_b     = (const float*)d_in[7];
    const float* xproj_w    = (const float*)d_in[8];
    const float* dt_w       = (const float*)d_in[9];
    const float* dt_b       = (const float*)d_in[10];
    const float* A_log      = (const float*)d_in[11];
    const float* D_param    = (const float*)d_in[12];
    const float* out_proj_w = (const float*)d_in[13];
    const float* fnorm_w    = (const float*)d_in[14];
    const float* fnorm_b    = (const float*)d_in[15];
    const float* head_w     = (const float*)d_in[16];
    float* out = (float*)d_out;
    float* ws  = (float*)d_ws;

    // workspace layout (floats)
    float* h   = ws;                  // B*L*DM      = 2,097,152
    float* xln = h   + 2097152;       // B*L*DM      = 2,097,152
    float* xz  = xln + 2097152;       // B*L*2DI     = 8,388,608
    float* xb  = xz  + 8388608;       // B*L*DI      = 4,194,304
    float* xp  = xb  + 4194304;       // B*L*XPD     =   327,680
    float* dlt = xp  + 327680;        // B*L*DI      = 4,194,304
    float* y   = dlt + 4194304;       // B*L*DI      = 4,194,304
    float* Pc  = y   + 4194304;       // B*NC*N*DI   = 2,097,152
    float* Sc  = Pc  + 2097152;       // B*NC*N*DI   = 2,097,152
    float* hst = Sc  + 2097152;       // B*NC*N*DI   = 2,097,152
    // total ~31.8M floats = 127 MB

    embed_k<<<B_ * L_ * DM_ / 256, 256, 0, stream>>>(tokens, tok_emb, pos_emb, h);

    for (int li = 0; li < NL_; ++li) {
        // x = LN(h)
        layernorm_k<<<B_ * L_, 256, 0, stream>>>(h, ln_w + li * DM_, ln_b + li * DM_,
                                                 xln, 1, 0);
        // xz = x @ in_proj_w^T   (2048 x 4096, K=1024)
        gemm_nt<false, false, false, false>
            <<<dim3(2 * DI_ / 64, B_ * L_ / 64), 256, 0, stream>>>(
            xln, DM_, in_proj_w + (size_t)li * 2 * DI_ * DM_, DM_,
            xz, 2 * DI_, nullptr, 2 * DI_, DM_);
        // x_branch = silu(conv(xz[...,:DI]))
        conv_silu<<<B_ * L_ * DI_ / 256, 256, 0, stream>>>(
            xz, conv_w + li * DI_ * K_, conv_b + li * DI_, xb);
        // xp = x_branch @ xproj_w^T   (2048 x 160, K=2048)
        gemm_nt<false, false, false, true>
            <<<dim3((XPD_ + 63) / 64, B_ * L_ / 64), 256, 0, stream>>>(
            xb, DI_, xproj_w + (size_t)li * XPD_ * DI_, DI_,
            xp, XPD_, nullptr, XPD_, DI_);
        // delta = softplus(dt_r @ dt_w^T + dt_b)   (2048 x 2048, K=128)
        gemm_nt<true, true, false, false>
            <<<dim3(DI_ / 64, B_ * L_ / 64), 256, 0, stream>>>(
            xp, XPD_, dt_w + (size_t)li * DI_ * DTR_, DTR_,
            dlt, DI_, dt_b + li * DI_, DI_, DTR_);
        // chunked selective scan
        ssm_pass1<<<B_ * NC_ * (DI_ / 256), 256, 0, stream>>>(
            xb, dlt, xp, A_log + li * DI_ * N_, Pc, Sc);
        ssm_scan<<<B_ * N_ * DI_ / 256, 256, 0, stream>>>(Pc, Sc, hst);
        ssm_pass2<<<B_ * NC_ * (DI_ / 256), 256, 0, stream>>>(
            xb, dlt, xp, A_log + li * DI_ * N_, D_param + li * DI_, xz, hst, y);
        // h = y @ out_proj_w^T + h   (2048 x 1024, K=2048, residual)
        gemm_nt<false, false, true, false>
            <<<dim3(DM_ / 64, B_ * L_ / 64), 256, 0, stream>>>(
            y, DI_, out_proj_w + (size_t)li * DM_ * DI_, DI_,
            h, DM_, nullptr, DM_, DI_);
    }

    // final LN on last token of each batch -> xln[0:8]
    layernorm_k<<<B_, 256, 0, stream>>>(h, fnorm_w, fnorm_b, xln, L_, L_ - 1);
    // logits
    head_k<<<B_ * P_, 256, 0, stream>>>(xln, head_w, out);
}

// Round 2
// 1934.978 us; speedup vs baseline: 1.5752x; 1.5752x over previous
//
#include <hip/hip_runtime.h>
#include <hip/hip_bf16.h>
#include <cstdint>
#include <cstddef>

#define B_    8
#define L_    256
#define DM_   1024
#define DI_   2048
#define N_    16
#define K_    4
#define NL_   4
#define DTR_  128
#define P_    97
#define XPD_  160   // DTR + 2N
#define CHUNK_ 32
#define NC_   8     // L / CHUNK

typedef __attribute__((ext_vector_type(8))) short short8;
typedef __attribute__((ext_vector_type(4))) float floatx4;

__device__ __forceinline__ void async16(const void* g, void* l)
{
    __builtin_amdgcn_global_load_lds(
        (const __attribute__((address_space(1))) void*)g,
        (__attribute__((address_space(3))) void*)l,
        16, 0, 0);
}

// ---------------------------------------------------------------------------
// Embedding: h[b,l,:] = tok_emb[tokens[b,l],:] + pos_emb[l,:]
// ---------------------------------------------------------------------------
__global__ __launch_bounds__(256)
void embed_k(const int* __restrict__ tokens, const float* __restrict__ te,
             const float* __restrict__ pe, float* __restrict__ h)
{
    int idx = blockIdx.x * 256 + threadIdx.x;   // over B*L*DM
    int m  = idx & (DM_ - 1);
    int bl = idx >> 10;
    int l  = bl & (L_ - 1);
    int tok = tokens[bl];
    h[idx] = te[tok * DM_ + m] + pe[l * DM_ + m];
}

// ---------------------------------------------------------------------------
// fp32 -> bf16 conversion (4 elems/thread)
// ---------------------------------------------------------------------------
__global__ __launch_bounds__(256)
void f32_to_bf16_k(const float* __restrict__ src, __hip_bfloat16* __restrict__ dst)
{
    int i = (blockIdx.x * 256 + threadIdx.x) * 4;
    float4 v = *(const float4*)(src + i);
    union { __hip_bfloat16 h[4]; ushort4 u; } t;
    t.h[0] = __float2bfloat16(v.x);
    t.h[1] = __float2bfloat16(v.y);
    t.h[2] = __float2bfloat16(v.z);
    t.h[3] = __float2bfloat16(v.w);
    *(ushort4*)(dst + i) = t.u;
}

// ---------------------------------------------------------------------------
// LayerNorm over DM=1024. One block per row. OT = float or __hip_bfloat16.
// ---------------------------------------------------------------------------
template<typename OT>
__global__ __launch_bounds__(256)
void layernorm_k(const float* __restrict__ in, const float* __restrict__ w,
                 const float* __restrict__ b, OT* __restrict__ out,
                 int rstep, int rbase)
{
    __shared__ float red[8];
    int row_in = blockIdx.x * rstep + rbase;
    const float* p = in + (size_t)row_in * DM_;
    int tid = threadIdx.x;
    float4 x = *(const float4*)(p + tid * 4);
    float s  = x.x + x.y + x.z + x.w;
    float s2 = x.x * x.x + x.y * x.y + x.z * x.z + x.w * x.w;
    #pragma unroll
    for (int o = 32; o > 0; o >>= 1) {
        s  += __shfl_down(s, o);
        s2 += __shfl_down(s2, o);
    }
    if ((tid & 63) == 0) { red[tid >> 6] = s; red[4 + (tid >> 6)] = s2; }
    __syncthreads();
    float st  = red[0] + red[1] + red[2] + red[3];
    float s2t = red[4] + red[5] + red[6] + red[7];
    float m   = st * (1.f / DM_);
    float var = s2t * (1.f / DM_) - m * m;
    float rs  = rsqrtf(var + 1e-5f);
    float4 wv = *(const float4*)(w + tid * 4);
    float4 bv = *(const float4*)(b + tid * 4);
    float o0 = (x.x - m) * rs * wv.x + bv.x;
    float o1 = (x.y - m) * rs * wv.y + bv.y;
    float o2 = (x.z - m) * rs * wv.z + bv.z;
    float o3 = (x.w - m) * rs * wv.w + bv.w;
    size_t ob = (size_t)blockIdx.x * DM_ + tid * 4;
    if constexpr (sizeof(OT) == 4) {
        *(float4*)((float*)out + ob) = make_float4(o0, o1, o2, o3);
    } else {
        union { __hip_bfloat16 h[4]; ushort4 u; } t;
        t.h[0] = __float2bfloat16(o0);
        t.h[1] = __float2bfloat16(o1);
        t.h[2] = __float2bfloat16(o2);
        t.h[3] = __float2bfloat16(o3);
        *(ushort4*)((__hip_bfloat16*)out + ob) = t.u;
    }
}

// ---------------------------------------------------------------------------
// bf16 MFMA GEMM (m97 recipe): C[m,n] = sum_k A[m,k]*Bw[n,k] (+= if RES)
// A: [M,K] bf16 row-major. Bw: [N,K] bf16 (weights, i.e. B^T). C fp32.
// 128x128 tile, 256 thr = 4 waves (2x2), BK=32, global_load_lds width 16.
// M,N multiples of 128; K multiple of 32.
// ---------------------------------------------------------------------------
template<bool RES>
__global__ __launch_bounds__(256)
void gemm_bf16(const __hip_bfloat16* __restrict__ A, int lda,
               const __hip_bfloat16* __restrict__ Bw, int ldb,
               float* __restrict__ C, int ldc, int Kdim)
{
    __shared__ __hip_bfloat16 As[128 * 32];
    __shared__ __hip_bfloat16 Bs[128 * 32];
    const int tid  = threadIdx.x;
    const int lane = tid & 63;
    const int wid  = tid >> 6;
    const int wm   = wid >> 1, wn = wid & 1;
    const int mbase = blockIdx.y * 128;
    const int nbase = blockIdx.x * 128;

    floatx4 acc[4][4] = {};

    // staging: each tile image is 128 rows x 64 B = 8192 B; thread tid covers
    // flat offsets tid*16 and tid*16+4096
    const int f0 = tid * 16;
    const int r0 = f0 >> 6, c0 = f0 & 63;
    const int f1 = f0 + 4096;
    const int r1 = f1 >> 6, c1 = f1 & 63;

    const int fr = lane & 15;          // row/col within 16-tile
    const int kq = (lane >> 4) * 8;    // k base for this lane's fragment

    for (int k0 = 0; k0 < Kdim; k0 += 32) {
        const char* Ag = (const char*)(A + (size_t)mbase * lda + k0);
        const char* Bg = (const char*)(Bw + (size_t)nbase * ldb + k0);
        async16(Ag + (size_t)r0 * lda * 2 + c0, (char*)As + f0);
        async16(Ag + (size_t)r1 * lda * 2 + c1, (char*)As + f1);
        async16(Bg + (size_t)r0 * ldb * 2 + c0, (char*)Bs + f0);
        async16(Bg + (size_t)r1 * ldb * 2 + c1, (char*)Bs + f1);
        __syncthreads();   // compiler emits vmcnt(0) drain before barrier

        short8 af[4], bf[4];
        #pragma unroll
        for (int i = 0; i < 4; ++i) {
            int m = wm * 64 + i * 16 + fr;
            af[i] = *(const short8*)(As + m * 32 + kq);
            int n = wn * 64 + i * 16 + fr;
            bf[i] = *(const short8*)(Bs + n * 32 + kq);
        }
        #pragma unroll
        for (int i = 0; i < 4; ++i)
            #pragma unroll
            for (int j = 0; j < 4; ++j)
                acc[i][j] = __builtin_amdgcn_mfma_f32_16x16x32_bf16(
                    af[i], bf[j], acc[i][j], 0, 0, 0);
        __syncthreads();
    }

    // epilogue: C/D layout col=lane&15, row=(lane>>4)*4+reg
    const int cq = lane >> 4;
    #pragma unroll
    for (int i = 0; i < 4; ++i) {
        #pragma unroll
        for (int j = 0; j < 4; ++j) {
            int col = nbase + wn * 64 + j * 16 + fr;
            #pragma unroll
            for (int r = 0; r < 4; ++r) {
                int row = mbase + wm * 64 + i * 16 + cq * 4 + r;
                size_t off = (size_t)row * ldc + col;
                float v = acc[i][j][r];
                if (RES) C[off] += v; else C[off] = v;
            }
        }
    }
}

// ---------------------------------------------------------------------------
// Generic fp32 GEMM (kept for the small xproj / dt matmuls)
// ---------------------------------------------------------------------------
template<bool BIAS, bool SOFTPLUS, bool RES, bool NBOUND>
__global__ __launch_bounds__(256)
void gemm_nt(const float* __restrict__ A, int lda,
             const float* __restrict__ Bw, int ldb,
             float* __restrict__ C, int ldc,
             const float* __restrict__ bias, int N, int Kdim)
{
    __shared__ float As[16][68];
    __shared__ float Bs[16][68];
    const int tid = threadIdx.x;
    const int tx = tid & 15, ty = tid >> 4;
    const int mbase = blockIdx.y * 64;
    const int nbase = blockIdx.x * 64;
    const int kk = tid & 15;
    const int r0 = tid >> 4;
    float acc[4][4] = {};

    for (int k0 = 0; k0 < Kdim; k0 += 16) {
        #pragma unroll
        for (int i = 0; i < 4; ++i) {
            int row = r0 + i * 16;
            As[kk][row] = A[(size_t)(mbase + row) * lda + k0 + kk];
            float v = 0.f;
            if (!NBOUND || (nbase + row) < N)
                v = Bw[(size_t)(nbase + row) * ldb + k0 + kk];
            Bs[kk][row] = v;
        }
        __syncthreads();
        #pragma unroll
        for (int k = 0; k < 16; ++k) {
            const float4 av = *(const float4*)&As[k][ty * 4];
            const float4 bv = *(const float4*)&Bs[k][tx * 4];
            const float aa[4] = {av.x, av.y, av.z, av.w};
            const float bb[4] = {bv.x, bv.y, bv.z, bv.w};
            #pragma unroll
            for (int i = 0; i < 4; ++i)
                #pragma unroll
                for (int j = 0; j < 4; ++j)
                    acc[i][j] = fmaf(aa[i], bb[j], acc[i][j]);
        }
        __syncthreads();
    }

    #pragma unroll
    for (int i = 0; i < 4; ++i) {
        int row = mbase + ty * 4 + i;
        if (NBOUND) {
            for (int j = 0; j < 4; ++j) {
                int col = nbase + tx * 4 + j;
                if (col < N) {
                    float v = acc[i][j];
                    if (BIAS) v += bias[col];
                    if (SOFTPLUS) v = (v > 20.f) ? v : log1pf(__expf(v));
                    size_t off = (size_t)row * ldc + col;
                    if (RES) C[off] += v; else C[off] = v;
                }
            }
        } else {
            float vv[4];
            #pragma unroll
            for (int j = 0; j < 4; ++j) {
                float v = acc[i][j];
                if (BIAS) v += bias[nbase + tx * 4 + j];
                if (SOFTPLUS) v = (v > 20.f) ? v : log1pf(__expf(v));
                vv[j] = v;
            }
            size_t off = (size_t)row * ldc + nbase + tx * 4;
            if (RES) {
                float4 old = *(const float4*)&C[off];
                vv[0] += old.x; vv[1] += old.y; vv[2] += old.z; vv[3] += old.w;
            }
            *(float4*)&C[off] = make_float4(vv[0], vv[1], vv[2], vv[3]);
        }
    }
}

// ---------------------------------------------------------------------------
// Causal depthwise conv (K=4) over L + SiLU. Input = xz[..., :DI].
// ---------------------------------------------------------------------------
__global__ __launch_bounds__(256)
void conv_silu(const float* __restrict__ xz, const float* __restrict__ cw,
               const float* __restrict__ cb, float* __restrict__ xb)
{
    int idx = blockIdx.x * 256 + threadIdx.x;   // over B*L*DI
    int d  = idx & (DI_ - 1);
    int bl = idx >> 11;
    int l  = bl & (L_ - 1);
    float s = cb[d];
    #pragma unroll
    for (int k = 0; k < 4; ++k) {
        int lk = l + k - 3;
        if (lk >= 0)
            s += cw[d * 4 + k] * xz[(size_t)(bl - l + lk) * (2 * DI_) + d];
    }
    xb[idx] = s / (1.f + __expf(-s));   // silu
}

// ---------------------------------------------------------------------------
// SSM chunked scan. Chunk layout for P/S/hstart: [b][c][n][d] (d coalesced).
// ---------------------------------------------------------------------------
__global__ __launch_bounds__(256)
void ssm_pass1(const float* __restrict__ xb, const float* __restrict__ dlt,
               const float* __restrict__ xp, const float* __restrict__ Alog,
               float* __restrict__ Pc, float* __restrict__ Sc)
{
    int blk = blockIdx.x;
    int dgrp = blk & 7, c = (blk >> 3) & 7, b = blk >> 6;
    int d = (dgrp << 8) + threadIdx.x;
    __shared__ float Bsh[CHUNK_][N_];
    for (int i = threadIdx.x; i < CHUNK_ * N_; i += 256) {
        int t = i >> 4, n = i & 15;
        Bsh[t][n] = xp[(size_t)(b * L_ + c * CHUNK_ + t) * XPD_ + DTR_ + n];
    }
    __syncthreads();
    float a[N_], hn[N_], Pn[N_];
    #pragma unroll
    for (int n = 0; n < N_; ++n) {
        a[n] = -__expf(Alog[d * N_ + n]);
        hn[n] = 0.f; Pn[n] = 1.f;
    }
    for (int t = 0; t < CHUNK_; ++t) {
        size_t off = (size_t)(b * L_ + c * CHUNK_ + t) * DI_ + d;
        float dt = dlt[off], xv = xb[off];
        float dx = dt * xv;
        #pragma unroll
        for (int n = 0; n < N_; ++n) {
            float dA = __expf(dt * a[n]);
            hn[n] = dA * hn[n] + dx * Bsh[t][n];
            Pn[n] *= dA;
        }
    }
    #pragma unroll
    for (int n = 0; n < N_; ++n) {
        size_t o = ((size_t)((b * NC_ + c) * N_ + n)) * DI_ + d;
        Pc[o] = Pn[n]; Sc[o] = hn[n];
    }
}

__global__ __launch_bounds__(256)
void ssm_scan(const float* __restrict__ Pc, const float* __restrict__ Sc,
              float* __restrict__ hstart)
{
    int idx = blockIdx.x * 256 + threadIdx.x;   // over B*N*DI
    int d = idx & (DI_ - 1);
    int bn = idx >> 11;
    int n = bn & 15, b = bn >> 4;
    float h = 0.f;
    for (int c = 0; c < NC_; ++c) {
        size_t o = ((size_t)((b * NC_ + c) * N_ + n)) * DI_ + d;
        hstart[o] = h;
        h = Pc[o] * h + Sc[o];
    }
}

// pass2: re-run chunk from hstart, emit y = (C.h + x*D) * silu(z) as bf16
__global__ __launch_bounds__(256)
void ssm_pass2(const float* __restrict__ xb, const float* __restrict__ dlt,
               const float* __restrict__ xp, const float* __restrict__ Alog,
               const float* __restrict__ Dp, const float* __restrict__ xz,
               const float* __restrict__ hstart, __hip_bfloat16* __restrict__ yout)
{
    int blk = blockIdx.x;
    int dgrp = blk & 7, c = (blk >> 3) & 7, b = blk >> 6;
    int d = (dgrp << 8) + threadIdx.x;
    __shared__ float Bsh[CHUNK_][N_], Csh[CHUNK_][N_];
    for (int i = threadIdx.x; i < CHUNK_ * 2 * N_; i += 256) {
        int t = i >> 5, j = i & 31;
        float v = xp[(size_t)(b * L_ + c * CHUNK_ + t) * XPD_ + DTR_ + j];
        if (j < 16) Bsh[t][j] = v; else Csh[t][j - 16] = v;
    }
    __syncthreads();
    float a[N_], hn[N_];
    #pragma unroll
    for (int n = 0; n < N_; ++n) {
        a[n] = -__expf(Alog[d * N_ + n]);
        hn[n] = hstart[((size_t)((b * NC_ + c) * N_ + n)) * DI_ + d];
    }
    float dpv = Dp[d];
    for (int t = 0; t < CHUNK_; ++t) {
        int l = c * CHUNK_ + t;
        size_t off = (size_t)(b * L_ + l) * DI_ + d;
        float dt = dlt[off], xv = xb[off];
        float dx = dt * xv;
        float yv = 0.f;
        #pragma unroll
        for (int n = 0; n < N_; ++n) {
            float dA = __expf(dt * a[n]);
            hn[n] = dA * hn[n] + dx * Bsh[t][n];
            yv += hn[n] * Csh[t][n];
        }
        yv += xv * dpv;
        float z = xz[(size_t)(b * L_ + l) * (2 * DI_) + DI_ + d];
        yout[off] = __float2bfloat16(yv * z / (1.f + __expf(-z)));
    }
}

// ---------------------------------------------------------------------------
// Head: out[b,p] = dot(hln[b,:], head_w[p,:])
// ---------------------------------------------------------------------------
__global__ __launch_bounds__(256)
void head_k(const float* __restrict__ hln, const float* __restrict__ hw,
            float* __restrict__ out)
{
    __shared__ float red[4];
    int b = blockIdx.x / P_;
    int p = blockIdx.x % P_;
    int tid = threadIdx.x;
    const float* av = hln + (size_t)b * DM_;
    const float* wv = hw + (size_t)p * DM_;
    float4 xa = *(const float4*)(av + tid * 4);
    float4 xw = *(const float4*)(wv + tid * 4);
    float s = xa.x * xw.x + xa.y * xw.y + xa.z * xw.z + xa.w * xw.w;
    #pragma unroll
    for (int o = 32; o > 0; o >>= 1) s += __shfl_down(s, o);
    if ((tid & 63) == 0) red[tid >> 6] = s;
    __syncthreads();
    if (tid == 0) out[blockIdx.x] = red[0] + red[1] + red[2] + red[3];
}

// ---------------------------------------------------------------------------
extern "C" void kernel_launch(void* const* d_in, const int* in_sizes, int n_in,
                              void* d_out, int out_size, void* d_ws, size_t ws_size,
                              hipStream_t stream)
{
    const int*   tokens     = (const int*)  d_in[0];
    const float* tok_emb    = (const float*)d_in[1];
    const float* pos_emb    = (const float*)d_in[2];
    const float* ln_w       = (const float*)d_in[3];
    const float* ln_b       = (const float*)d_in[4];
    const float* in_proj_w  = (const float*)d_in[5];
    const float* conv_w     = (const float*)d_in[6];
    const float* conv_b     = (const float*)d_in[7];
    const float* xproj_w    = (const float*)d_in[8];
    const float* dt_w       = (const float*)d_in[9];
    const float* dt_b       = (const float*)d_in[10];
    const float* A_log      = (const float*)d_in[11];
    const float* D_param    = (const float*)d_in[12];
    const float* out_proj_w = (const float*)d_in[13];
    const float* fnorm_w    = (const float*)d_in[14];
    const float* fnorm_b    = (const float*)d_in[15];
    const float* head_w     = (const float*)d_in[16];
    float* out = (float*)d_out;
    float* ws  = (float*)d_ws;

    // fp32 workspace (floats)
    float* h    = ws;                  // B*L*DM    = 2,097,152
    float* xz   = h    + 2097152;      // B*L*2DI   = 8,388,608
    float* xb   = xz   + 8388608;      // B*L*DI    = 4,194,304
    float* xp   = xb   + 4194304;      // B*L*XPD   =   327,680
    float* dlt  = xp   + 327680;       // B*L*DI    = 4,194,304
    float* Pc   = dlt  + 4194304;      // B*NC*N*DI = 2,097,152
    float* Sc   = Pc   + 2097152;      // 2,097,152
    float* hst  = Sc   + 2097152;      // 2,097,152
    float* hfin = hst  + 2097152;      // B*DM      = 8,192
    // bf16 workspace
    __hip_bfloat16* bfbase = (__hip_bfloat16*)(hfin + 8192);
    __hip_bfloat16* xln_b = bfbase;              // B*L*DM  = 2,097,152
    __hip_bfloat16* y_b   = xln_b + 2097152;     // B*L*DI  = 4,194,304
    __hip_bfloat16* ipw_b = y_b   + 4194304;     // 2DI*DM  = 4,194,304 (per layer)
    __hip_bfloat16* opw_b = ipw_b + 4194304;     // DM*DI   = 2,097,152 (per layer)
    // total ~= 127 MB

    embed_k<<<B_ * L_ * DM_ / 256, 256, 0, stream>>>(tokens, tok_emb, pos_emb, h);

    for (int li = 0; li < NL_; ++li) {
        // per-layer weight conversion to bf16
        f32_to_bf16_k<<<2 * DI_ * DM_ / 1024, 256, 0, stream>>>(
            in_proj_w + (size_t)li * 2 * DI_ * DM_, ipw_b);
        f32_to_bf16_k<<<DM_ * DI_ / 1024, 256, 0, stream>>>(
            out_proj_w + (size_t)li * DM_ * DI_, opw_b);

        // x = LN(h) -> bf16
        layernorm_k<__hip_bfloat16><<<B_ * L_, 256, 0, stream>>>(
            h, ln_w + li * DM_, ln_b + li * DM_, xln_b, 1, 0);

        // xz = x @ in_proj_w^T   (2048 x 4096, K=1024)  [bf16 MFMA]
        gemm_bf16<false><<<dim3(2 * DI_ / 128, B_ * L_ / 128), 256, 0, stream>>>(
            xln_b, DM_, ipw_b, DM_, xz, 2 * DI_, DM_);

        // x_branch = silu(conv(xz[...,:DI]))
        conv_silu<<<B_ * L_ * DI_ / 256, 256, 0, stream>>>(
            xz, conv_w + li * DI_ * K_, conv_b + li * DI_, xb);

        // xp = x_branch @ xproj_w^T   (2048 x 160, K=2048)  [fp32]
        gemm_nt<false, false, false, true>
            <<<dim3((XPD_ + 63) / 64, B_ * L_ / 64), 256, 0, stream>>>(
            xb, DI_, xproj_w + (size_t)li * XPD_ * DI_, DI_,
            xp, XPD_, nullptr, XPD_, DI_);

        // delta = softplus(dt_r @ dt_w^T + dt_b)   (2048 x 2048, K=128)  [fp32]
        gemm_nt<true, true, false, false>
            <<<dim3(DI_ / 64, B_ * L_ / 64), 256, 0, stream>>>(
            xp, XPD_, dt_w + (size_t)li * DI_ * DTR_, DTR_,
            dlt, DI_, dt_b + li * DI_, DI_, DTR_);

        // chunked selective scan
        ssm_pass1<<<B_ * NC_ * (DI_ / 256), 256, 0, stream>>>(
            xb, dlt, xp, A_log + li * DI_ * N_, Pc, Sc);
        ssm_scan<<<B_ * N_ * DI_ / 256, 256, 0, stream>>>(Pc, Sc, hst);
        ssm_pass2<<<B_ * NC_ * (DI_ / 256), 256, 0, stream>>>(
            xb, dlt, xp, A_log + li * DI_ * N_, D_param + li * DI_, xz, hst, y_b);

        // h = y @ out_proj_w^T + h   (2048 x 1024, K=2048, residual)  [bf16 MFMA]
        gemm_bf16<true><<<dim3(DM_ / 128, B_ * L_ / 128), 256, 0, stream>>>(
            y_b, DI_, opw_b, DI_, h, DM_, DI_);
    }

    // final LN on last token of each batch
    layernorm_k<float><<<B_, 256, 0, stream>>>(h, fnorm_w, fnorm_b, hfin, L_, L_ - 1);
    // logits
    head_k<<<B_ * P_, 256, 0, stream>>>(hfin, head_w, out);
}

// Round 3
// 1062.600 us; speedup vs baseline: 2.8684x; 1.8210x over previous
//
#include <hip/hip_runtime.h>
#include <hip/hip_bf16.h>
#include <cstdint>
#include <cstddef>

#define B_    8
#define L_    256
#define DM_   1024
#define DI_   2048
#define N_    16
#define K_    4
#define NL_   4
#define DTR_  128
#define P_    97
#define XPD_  160   // DTR + 2N
#define CHUNK_ 32
#define NC_   8     // L / CHUNK

typedef __attribute__((ext_vector_type(8))) short short8;
typedef __attribute__((ext_vector_type(4))) float floatx4;

__device__ __forceinline__ void async16(const void* g, void* l)
{
    __builtin_amdgcn_global_load_lds(
        (const __attribute__((address_space(1))) void*)g,
        (__attribute__((address_space(3))) void*)l,
        16, 0, 0);
}

// ---------------------------------------------------------------------------
// Embedding
// ---------------------------------------------------------------------------
__global__ __launch_bounds__(256)
void embed_k(const int* __restrict__ tokens, const float* __restrict__ te,
             const float* __restrict__ pe, float* __restrict__ h)
{
    int idx = blockIdx.x * 256 + threadIdx.x;
    int m  = idx & (DM_ - 1);
    int bl = idx >> 10;
    int l  = bl & (L_ - 1);
    int tok = tokens[bl];
    h[idx] = te[tok * DM_ + m] + pe[l * DM_ + m];
}

// ---------------------------------------------------------------------------
// fp32 -> bf16 conversion (4 elems/thread)
// ---------------------------------------------------------------------------
__global__ __launch_bounds__(256)
void f32_to_bf16_k(const float* __restrict__ src, __hip_bfloat16* __restrict__ dst)
{
    int i = (blockIdx.x * 256 + threadIdx.x) * 4;
    float4 v = *(const float4*)(src + i);
    union { __hip_bfloat16 h[4]; ushort4 u; } t;
    t.h[0] = __float2bfloat16(v.x);
    t.h[1] = __float2bfloat16(v.y);
    t.h[2] = __float2bfloat16(v.z);
    t.h[3] = __float2bfloat16(v.w);
    *(ushort4*)(dst + i) = t.u;
}

// ---------------------------------------------------------------------------
// LayerNorm over DM=1024
// ---------------------------------------------------------------------------
template<typename OT>
__global__ __launch_bounds__(256)
void layernorm_k(const float* __restrict__ in, const float* __restrict__ w,
                 const float* __restrict__ b, OT* __restrict__ out,
                 int rstep, int rbase)
{
    __shared__ float red[8];
    int row_in = blockIdx.x * rstep + rbase;
    const float* p = in + (size_t)row_in * DM_;
    int tid = threadIdx.x;
    float4 x = *(const float4*)(p + tid * 4);
    float s  = x.x + x.y + x.z + x.w;
    float s2 = x.x * x.x + x.y * x.y + x.z * x.z + x.w * x.w;
    #pragma unroll
    for (int o = 32; o > 0; o >>= 1) {
        s  += __shfl_down(s, o);
        s2 += __shfl_down(s2, o);
    }
    if ((tid & 63) == 0) { red[tid >> 6] = s; red[4 + (tid >> 6)] = s2; }
    __syncthreads();
    float st  = red[0] + red[1] + red[2] + red[3];
    float s2t = red[4] + red[5] + red[6] + red[7];
    float m   = st * (1.f / DM_);
    float var = s2t * (1.f / DM_) - m * m;
    float rs  = rsqrtf(var + 1e-5f);
    float4 wv = *(const float4*)(w + tid * 4);
    float4 bv = *(const float4*)(b + tid * 4);
    float o0 = (x.x - m) * rs * wv.x + bv.x;
    float o1 = (x.y - m) * rs * wv.y + bv.y;
    float o2 = (x.z - m) * rs * wv.z + bv.z;
    float o3 = (x.w - m) * rs * wv.w + bv.w;
    size_t ob = (size_t)blockIdx.x * DM_ + tid * 4;
    if constexpr (sizeof(OT) == 4) {
        *(float4*)((float*)out + ob) = make_float4(o0, o1, o2, o3);
    } else {
        union { __hip_bfloat16 h[4]; ushort4 u; } t;
        t.h[0] = __float2bfloat16(o0);
        t.h[1] = __float2bfloat16(o1);
        t.h[2] = __float2bfloat16(o2);
        t.h[3] = __float2bfloat16(o3);
        *(ushort4*)((__hip_bfloat16*)out + ob) = t.u;
    }
}

// ---------------------------------------------------------------------------
// bf16 MFMA GEMM, 128x128 tile, BK=32, global_load_lds w16.
// MODE 0: C = A@Bw^T.  MODE 2: split-K partial -> Cp[z][M][ldc], z=blockIdx.z,
//         K range [z*Kp, (z+1)*Kp).
// ---------------------------------------------------------------------------
template<int MODE>
__global__ __launch_bounds__(256)
void gemm_bf16(const __hip_bfloat16* __restrict__ A, int lda,
               const __hip_bfloat16* __restrict__ Bw, int ldb,
               float* __restrict__ C, int ldc, int Kp)
{
    __shared__ __hip_bfloat16 As[128 * 32];
    __shared__ __hip_bfloat16 Bs[128 * 32];
    const int tid  = threadIdx.x;
    const int lane = tid & 63;
    const int wid  = tid >> 6;
    const int wm   = wid >> 1, wn = wid & 1;
    const int mbase = blockIdx.y * 128;
    const int nbase = blockIdx.x * 128;
    const int koff  = (MODE == 2) ? blockIdx.z * Kp : 0;

    floatx4 acc[4][4] = {};

    const int f0 = tid * 16;
    const int r0 = f0 >> 6, c0 = f0 & 63;
    const int f1 = f0 + 4096;
    const int r1 = f1 >> 6, c1 = f1 & 63;

    const int fr = lane & 15;
    const int kq = (lane >> 4) * 8;

    for (int k0 = koff; k0 < koff + Kp; k0 += 32) {
        const char* Ag = (const char*)(A + (size_t)mbase * lda + k0);
        const char* Bg = (const char*)(Bw + (size_t)nbase * ldb + k0);
        async16(Ag + (size_t)r0 * lda * 2 + c0, (char*)As + f0);
        async16(Ag + (size_t)r1 * lda * 2 + c1, (char*)As + f1);
        async16(Bg + (size_t)r0 * ldb * 2 + c0, (char*)Bs + f0);
        async16(Bg + (size_t)r1 * ldb * 2 + c1, (char*)Bs + f1);
        __syncthreads();

        short8 af[4], bf[4];
        #pragma unroll
        for (int i = 0; i < 4; ++i) {
            int m = wm * 64 + i * 16 + fr;
            af[i] = *(const short8*)(As + m * 32 + kq);
            int n = wn * 64 + i * 16 + fr;
            bf[i] = *(const short8*)(Bs + n * 32 + kq);
        }
        #pragma unroll
        for (int i = 0; i < 4; ++i)
            #pragma unroll
            for (int j = 0; j < 4; ++j)
                acc[i][j] = __builtin_amdgcn_mfma_f32_16x16x32_bf16(
                    af[i], bf[j], acc[i][j], 0, 0, 0);
        __syncthreads();
    }

    const int cq = lane >> 4;
    size_t zoff = (MODE == 2) ? (size_t)blockIdx.z * (gridDim.y * 128) * ldc : 0;
    #pragma unroll
    for (int i = 0; i < 4; ++i) {
        #pragma unroll
        for (int j = 0; j < 4; ++j) {
            int col = nbase + wn * 64 + j * 16 + fr;
            #pragma unroll
            for (int r = 0; r < 4; ++r) {
                int row = mbase + wm * 64 + i * 16 + cq * 4 + r;
                C[zoff + (size_t)row * ldc + col] = acc[i][j][r];
            }
        }
    }
}

// ---------------------------------------------------------------------------
// fp32 GEMM 64x64 tile (dt matmul): full-K, bias+softplus
// ---------------------------------------------------------------------------
template<bool BIAS, bool SOFTPLUS>
__global__ __launch_bounds__(256)
void gemm_nt(const float* __restrict__ A, int lda,
             const float* __restrict__ Bw, int ldb,
             float* __restrict__ C, int ldc,
             const float* __restrict__ bias, int Kdim)
{
    __shared__ float As[16][68];
    __shared__ float Bs[16][68];
    const int tid = threadIdx.x;
    const int tx = tid & 15, ty = tid >> 4;
    const int mbase = blockIdx.y * 64;
    const int nbase = blockIdx.x * 64;
    const int kk = tid & 15;
    const int r0 = tid >> 4;
    float acc[4][4] = {};

    for (int k0 = 0; k0 < Kdim; k0 += 16) {
        #pragma unroll
        for (int i = 0; i < 4; ++i) {
            int row = r0 + i * 16;
            As[kk][row] = A[(size_t)(mbase + row) * lda + k0 + kk];
            Bs[kk][row] = Bw[(size_t)(nbase + row) * ldb + k0 + kk];
        }
        __syncthreads();
        #pragma unroll
        for (int k = 0; k < 16; ++k) {
            const float4 av = *(const float4*)&As[k][ty * 4];
            const float4 bv = *(const float4*)&Bs[k][tx * 4];
            const float aa[4] = {av.x, av.y, av.z, av.w};
            const float bb[4] = {bv.x, bv.y, bv.z, bv.w};
            #pragma unroll
            for (int i = 0; i < 4; ++i)
                #pragma unroll
                for (int j = 0; j < 4; ++j)
                    acc[i][j] = fmaf(aa[i], bb[j], acc[i][j]);
        }
        __syncthreads();
    }

    #pragma unroll
    for (int i = 0; i < 4; ++i) {
        int row = mbase + ty * 4 + i;
        float vv[4];
        #pragma unroll
        for (int j = 0; j < 4; ++j) {
            float v = acc[i][j];
            if (BIAS) v += bias[nbase + tx * 4 + j];
            if (SOFTPLUS) v = (v > 20.f) ? v : log1pf(__expf(v));
            vv[j] = v;
        }
        *(float4*)&C[(size_t)row * ldc + nbase + tx * 4] =
            make_float4(vv[0], vv[1], vv[2], vv[3]);
    }
}

// ---------------------------------------------------------------------------
// fp32 split-K GEMM partials (xproj): z=blockIdx.z covers K [z*Kp,(z+1)*Kp).
// Cp layout [z][M][ldc]; N bounded (cols >= N dropped).
// ---------------------------------------------------------------------------
__global__ __launch_bounds__(256)
void gemm_nt_part(const float* __restrict__ A, int lda,
                  const float* __restrict__ Bw, int ldb,
                  float* __restrict__ Cp, int ldc, int Nb, int Kp)
{
    __shared__ float As[16][68];
    __shared__ float Bs[16][68];
    const int tid = threadIdx.x;
    const int tx = tid & 15, ty = tid >> 4;
    const int mbase = blockIdx.y * 64;
    const int nbase = blockIdx.x * 64;
    const int kk = tid & 15;
    const int r0 = tid >> 4;
    const int koff = blockIdx.z * Kp;
    float acc[4][4] = {};

    for (int k0 = koff; k0 < koff + Kp; k0 += 16) {
        #pragma unroll
        for (int i = 0; i < 4; ++i) {
            int row = r0 + i * 16;
            As[kk][row] = A[(size_t)(mbase + row) * lda + k0 + kk];
            float v = 0.f;
            if ((nbase + row) < Nb)
                v = Bw[(size_t)(nbase + row) * ldb + k0 + kk];
            Bs[kk][row] = v;
        }
        __syncthreads();
        #pragma unroll
        for (int k = 0; k < 16; ++k) {
            const float4 av = *(const float4*)&As[k][ty * 4];
            const float4 bv = *(const float4*)&Bs[k][tx * 4];
            const float aa[4] = {av.x, av.y, av.z, av.w};
            const float bb[4] = {bv.x, bv.y, bv.z, bv.w};
            #pragma unroll
            for (int i = 0; i < 4; ++i)
                #pragma unroll
                for (int j = 0; j < 4; ++j)
                    acc[i][j] = fmaf(aa[i], bb[j], acc[i][j]);
        }
        __syncthreads();
    }

    size_t zoff = (size_t)blockIdx.z * (gridDim.y * 64) * ldc;
    #pragma unroll
    for (int i = 0; i < 4; ++i) {
        int row = mbase + ty * 4 + i;
        #pragma unroll
        for (int j = 0; j < 4; ++j) {
            int col = nbase + tx * 4 + j;
            if (col < Nb)
                Cp[zoff + (size_t)row * ldc + col] = acc[i][j];
        }
    }
}

// ---------------------------------------------------------------------------
// Split-K reduction: dst[i] (+)= sum_z p[z*stride + i], float4 vectorized
// ---------------------------------------------------------------------------
template<int PARTS, bool ACCUM>
__global__ __launch_bounds__(256)
void reduce_k(const float* __restrict__ p, float* __restrict__ dst, size_t stride)
{
    size_t i = ((size_t)blockIdx.x * 256 + threadIdx.x) * 4;
    float4 s = *(const float4*)(p + i);
    #pragma unroll
    for (int z = 1; z < PARTS; ++z) {
        float4 v = *(const float4*)(p + z * stride + i);
        s.x += v.x; s.y += v.y; s.z += v.z; s.w += v.w;
    }
    if (ACCUM) {
        float4 d = *(const float4*)(dst + i);
        s.x += d.x; s.y += d.y; s.z += d.z; s.w += d.w;
    }
    *(float4*)(dst + i) = s;
}

// ---------------------------------------------------------------------------
// Causal depthwise conv (K=4) + SiLU
// ---------------------------------------------------------------------------
__global__ __launch_bounds__(256)
void conv_silu(const float* __restrict__ xz, const float* __restrict__ cw,
               const float* __restrict__ cb, float* __restrict__ xb)
{
    int idx = blockIdx.x * 256 + threadIdx.x;
    int d  = idx & (DI_ - 1);
    int bl = idx >> 11;
    int l  = bl & (L_ - 1);
    float s = cb[d];
    #pragma unroll
    for (int k = 0; k < 4; ++k) {
        int lk = l + k - 3;
        if (lk >= 0)
            s += cw[d * 4 + k] * xz[(size_t)(bl - l + lk) * (2 * DI_) + d];
    }
    xb[idx] = s / (1.f + __expf(-s));
}

// ---------------------------------------------------------------------------
// SSM chunked scan
// ---------------------------------------------------------------------------
__global__ __launch_bounds__(256)
void ssm_pass1(const float* __restrict__ xb, const float* __restrict__ dlt,
               const float* __restrict__ xp, const float* __restrict__ Alog,
               float* __restrict__ Pc, float* __restrict__ Sc)
{
    int blk = blockIdx.x;
    int dgrp = blk & 7, c = (blk >> 3) & 7, b = blk >> 6;
    int d = (dgrp << 8) + threadIdx.x;
    __shared__ float Bsh[CHUNK_][N_];
    for (int i = threadIdx.x; i < CHUNK_ * N_; i += 256) {
        int t = i >> 4, n = i & 15;
        Bsh[t][n] = xp[(size_t)(b * L_ + c * CHUNK_ + t) * XPD_ + DTR_ + n];
    }
    __syncthreads();
    float a[N_], hn[N_], Pn[N_];
    #pragma unroll
    for (int n = 0; n < N_; ++n) {
        a[n] = -__expf(Alog[d * N_ + n]);
        hn[n] = 0.f; Pn[n] = 1.f;
    }
    for (int t = 0; t < CHUNK_; ++t) {
        size_t off = (size_t)(b * L_ + c * CHUNK_ + t) * DI_ + d;
        float dt = dlt[off], xv = xb[off];
        float dx = dt * xv;
        #pragma unroll
        for (int n = 0; n < N_; ++n) {
            float dA = __expf(dt * a[n]);
            hn[n] = dA * hn[n] + dx * Bsh[t][n];
            Pn[n] *= dA;
        }
    }
    #pragma unroll
    for (int n = 0; n < N_; ++n) {
        size_t o = ((size_t)((b * NC_ + c) * N_ + n)) * DI_ + d;
        Pc[o] = Pn[n]; Sc[o] = hn[n];
    }
}

__global__ __launch_bounds__(256)
void ssm_scan(const float* __restrict__ Pc, const float* __restrict__ Sc,
              float* __restrict__ hstart)
{
    int idx = blockIdx.x * 256 + threadIdx.x;
    int d = idx & (DI_ - 1);
    int bn = idx >> 11;
    int n = bn & 15, b = bn >> 4;
    float h = 0.f;
    for (int c = 0; c < NC_; ++c) {
        size_t o = ((size_t)((b * NC_ + c) * N_ + n)) * DI_ + d;
        hstart[o] = h;
        h = Pc[o] * h + Sc[o];
    }
}

__global__ __launch_bounds__(256)
void ssm_pass2(const float* __restrict__ xb, const float* __restrict__ dlt,
               const float* __restrict__ xp, const float* __restrict__ Alog,
               const float* __restrict__ Dp, const float* __restrict__ xz,
               const float* __restrict__ hstart, __hip_bfloat16* __restrict__ yout)
{
    int blk = blockIdx.x;
    int dgrp = blk & 7, c = (blk >> 3) & 7, b = blk >> 6;
    int d = (dgrp << 8) + threadIdx.x;
    __shared__ float Bsh[CHUNK_][N_], Csh[CHUNK_][N_];
    for (int i = threadIdx.x; i < CHUNK_ * 2 * N_; i += 256) {
        int t = i >> 5, j = i & 31;
        float v = xp[(size_t)(b * L_ + c * CHUNK_ + t) * XPD_ + DTR_ + j];
        if (j < 16) Bsh[t][j] = v; else Csh[t][j - 16] = v;
    }
    __syncthreads();
    float a[N_], hn[N_];
    #pragma unroll
    for (int n = 0; n < N_; ++n) {
        a[n] = -__expf(Alog[d * N_ + n]);
        hn[n] = hstart[((size_t)((b * NC_ + c) * N_ + n)) * DI_ + d];
    }
    float dpv = Dp[d];
    for (int t = 0; t < CHUNK_; ++t) {
        int l = c * CHUNK_ + t;
        size_t off = (size_t)(b * L_ + l) * DI_ + d;
        float dt = dlt[off], xv = xb[off];
        float dx = dt * xv;
        float yv = 0.f;
        #pragma unroll
        for (int n = 0; n < N_; ++n) {
            float dA = __expf(dt * a[n]);
            hn[n] = dA * hn[n] + dx * Bsh[t][n];
            yv += hn[n] * Csh[t][n];
        }
        yv += xv * dpv;
        float z = xz[(size_t)(b * L_ + l) * (2 * DI_) + DI_ + d];
        yout[off] = __float2bfloat16(yv * z / (1.f + __expf(-z)));
    }
}

// ---------------------------------------------------------------------------
// Head
// ---------------------------------------------------------------------------
__global__ __launch_bounds__(256)
void head_k(const float* __restrict__ hln, const float* __restrict__ hw,
            float* __restrict__ out)
{
    __shared__ float red[4];
    int b = blockIdx.x / P_;
    int p = blockIdx.x % P_;
    int tid = threadIdx.x;
    const float* av = hln + (size_t)b * DM_;
    const float* wv = hw + (size_t)p * DM_;
    float4 xa = *(const float4*)(av + tid * 4);
    float4 xw = *(const float4*)(wv + tid * 4);
    float s = xa.x * xw.x + xa.y * xw.y + xa.z * xw.z + xa.w * xw.w;
    #pragma unroll
    for (int o = 32; o > 0; o >>= 1) s += __shfl_down(s, o);
    if ((tid & 63) == 0) red[tid >> 6] = s;
    __syncthreads();
    if (tid == 0) out[blockIdx.x] = red[0] + red[1] + red[2] + red[3];
}

// ---------------------------------------------------------------------------
extern "C" void kernel_launch(void* const* d_in, const int* in_sizes, int n_in,
                              void* d_out, int out_size, void* d_ws, size_t ws_size,
                              hipStream_t stream)
{
    const int*   tokens     = (const int*)  d_in[0];
    const float* tok_emb    = (const float*)d_in[1];
    const float* pos_emb    = (const float*)d_in[2];
    const float* ln_w       = (const float*)d_in[3];
    const float* ln_b       = (const float*)d_in[4];
    const float* in_proj_w  = (const float*)d_in[5];
    const float* conv_w     = (const float*)d_in[6];
    const float* conv_b     = (const float*)d_in[7];
    const float* xproj_w    = (const float*)d_in[8];
    const float* dt_w       = (const float*)d_in[9];
    const float* dt_b       = (const float*)d_in[10];
    const float* A_log      = (const float*)d_in[11];
    const float* D_param    = (const float*)d_in[12];
    const float* out_proj_w = (const float*)d_in[13];
    const float* fnorm_w    = (const float*)d_in[14];
    const float* fnorm_b    = (const float*)d_in[15];
    const float* head_w     = (const float*)d_in[16];
    float* out = (float*)d_out;
    float* ws  = (float*)d_ws;

    // fp32 workspace (floats)
    float* h    = ws;                  // B*L*DM    = 2,097,152
    float* xz   = h    + 2097152;      // B*L*2DI   = 8,388,608
    float* xb   = xz   + 8388608;      // B*L*DI    = 4,194,304
    float* xp   = xb   + 4194304;      // B*L*XPD   =   327,680
    float* dlt  = xp   + 327680;       // B*L*DI    = 4,194,304
    float* Pc   = dlt  + 4194304;      // B*NC*N*DI = 2,097,152
    float* Sc   = Pc   + 2097152;      // 2,097,152
    float* hst  = Sc   + 2097152;      // 2,097,152
    float* hfin = hst  + 2097152;      // B*DM      = 8,192
    // bf16 workspace
    __hip_bfloat16* bfbase = (__hip_bfloat16*)(hfin + 8192);
    __hip_bfloat16* xln_b = bfbase;              // B*L*DM  = 2,097,152
    __hip_bfloat16* y_b   = xln_b + 2097152;     // B*L*DI  = 4,194,304
    __hip_bfloat16* ipw_b = y_b   + 4194304;     // 2DI*DM  = 4,194,304
    __hip_bfloat16* opw_b = ipw_b + 4194304;     // DM*DI   = 2,097,152
    // split-K partial buffers (aliased onto dead regions):
    //  part_xp: 16 parts x 2048 x 160 = 5,242,880 fl — lives only between
    //    xproj-split and its reduce; aliases Pc/Sc/hst (6.29M, used later).
    float* part_xp = Pc;
    //  part_h: 2 parts x 2048 x 1024 = 4,194,304 fl — lives only between
    //    out_proj-split and reduce; aliases xz (dead after ssm_pass2).
    float* part_h = xz;

    embed_k<<<B_ * L_ * DM_ / 256, 256, 0, stream>>>(tokens, tok_emb, pos_emb, h);

    for (int li = 0; li < NL_; ++li) {
        f32_to_bf16_k<<<2 * DI_ * DM_ / 1024, 256, 0, stream>>>(
            in_proj_w + (size_t)li * 2 * DI_ * DM_, ipw_b);
        f32_to_bf16_k<<<DM_ * DI_ / 1024, 256, 0, stream>>>(
            out_proj_w + (size_t)li * DM_ * DI_, opw_b);

        // x = LN(h) -> bf16
        layernorm_k<__hip_bfloat16><<<B_ * L_, 256, 0, stream>>>(
            h, ln_w + li * DM_, ln_b + li * DM_, xln_b, 1, 0);

        // xz = x @ in_proj_w^T   (2048 x 4096, K=1024)  [bf16 MFMA]
        gemm_bf16<0><<<dim3(2 * DI_ / 128, B_ * L_ / 128), 256, 0, stream>>>(
            xln_b, DM_, ipw_b, DM_, xz, 2 * DI_, DM_);

        // x_branch = silu(conv(xz[...,:DI]))
        conv_silu<<<B_ * L_ * DI_ / 256, 256, 0, stream>>>(
            xz, conv_w + li * DI_ * K_, conv_b + li * DI_, xb);

        // xp = x_branch @ xproj_w^T  (2048 x 160, K=2048) [fp32, split-K 16]
        gemm_nt_part<<<dim3(3, B_ * L_ / 64, 16), 256, 0, stream>>>(
            xb, DI_, xproj_w + (size_t)li * XPD_ * DI_, DI_,
            part_xp, XPD_, XPD_, DI_ / 16);
        reduce_k<16, false><<<B_ * L_ * XPD_ / 1024, 256, 0, stream>>>(
            part_xp, xp, (size_t)B_ * L_ * XPD_);

        // delta = softplus(dt_r @ dt_w^T + dt_b)  (2048 x 2048, K=128) [fp32]
        gemm_nt<true, true><<<dim3(DI_ / 64, B_ * L_ / 64), 256, 0, stream>>>(
            xp, XPD_, dt_w + (size_t)li * DI_ * DTR_, DTR_,
            dlt, DI_, dt_b + li * DI_, DTR_);

        // chunked selective scan
        ssm_pass1<<<B_ * NC_ * (DI_ / 256), 256, 0, stream>>>(
            xb, dlt, xp, A_log + li * DI_ * N_, Pc, Sc);
        ssm_scan<<<B_ * N_ * DI_ / 256, 256, 0, stream>>>(Pc, Sc, hst);
        ssm_pass2<<<B_ * NC_ * (DI_ / 256), 256, 0, stream>>>(
            xb, dlt, xp, A_log + li * DI_ * N_, D_param + li * DI_, xz, hst, y_b);

        // h += y @ out_proj_w^T  (2048 x 1024, K=2048) [bf16 MFMA, split-K 2]
        gemm_bf16<2><<<dim3(DM_ / 128, B_ * L_ / 128, 2), 256, 0, stream>>>(
            y_b, DI_, opw_b, DI_, part_h, DM_, DI_ / 2);
        reduce_k<2, true><<<B_ * L_ * DM_ / 1024, 256, 0, stream>>>(
            part_h, h, (size_t)B_ * L_ * DM_);
    }

    // final LN on last token of each batch
    layernorm_k<float><<<B_, 256, 0, stream>>>(h, fnorm_w, fnorm_b, hfin, L_, L_ - 1);
    // logits
    head_k<<<B_ * P_, 256, 0, stream>>>(hfin, head_w, out);
}

// Round 4
// 952.291 us; speedup vs baseline: 3.2006x; 1.1158x over previous
//
#include <hip/hip_runtime.h>
#include <hip/hip_bf16.h>
#include <cstdint>
#include <cstddef>

#define B_    8
#define L_    256
#define DM_   1024
#define DI_   2048
#define N_    16
#define K_    4
#define NL_   4
#define DTR_  128
#define P_    97
#define XPD_  160   // DTR + 2N
#define CHUNK_ 32
#define NC_   8     // L / CHUNK

typedef __attribute__((ext_vector_type(8))) short short8;
typedef __attribute__((ext_vector_type(4))) float floatx4;

__device__ __forceinline__ void async16(const void* g, void* l)
{
    __builtin_amdgcn_global_load_lds(
        (const __attribute__((address_space(1))) void*)g,
        (__attribute__((address_space(3))) void*)l,
        16, 0, 0);
}

// ---------------------------------------------------------------------------
// Embedding
// ---------------------------------------------------------------------------
__global__ __launch_bounds__(256)
void embed_k(const int* __restrict__ tokens, const float* __restrict__ te,
             const float* __restrict__ pe, float* __restrict__ h)
{
    int idx = blockIdx.x * 256 + threadIdx.x;
    int m  = idx & (DM_ - 1);
    int bl = idx >> 10;
    int l  = bl & (L_ - 1);
    int tok = tokens[bl];
    h[idx] = te[tok * DM_ + m] + pe[l * DM_ + m];
}

// ---------------------------------------------------------------------------
// fp32 -> bf16 bulk conversion (4 elems/thread)
// ---------------------------------------------------------------------------
__global__ __launch_bounds__(256)
void f32_to_bf16_k(const float* __restrict__ src, __hip_bfloat16* __restrict__ dst)
{
    size_t i = ((size_t)blockIdx.x * 256 + threadIdx.x) * 4;
    float4 v = *(const float4*)(src + i);
    union { __hip_bfloat16 h[4]; ushort4 u; } t;
    t.h[0] = __float2bfloat16(v.x);
    t.h[1] = __float2bfloat16(v.y);
    t.h[2] = __float2bfloat16(v.z);
    t.h[3] = __float2bfloat16(v.w);
    *(ushort4*)(dst + i) = t.u;
}

// xproj weights: [NL][160][2048] fp32 -> [NL][256][2048] bf16, rows>=160 zero
__global__ __launch_bounds__(256)
void conv_xpw_k(const float* __restrict__ src, __hip_bfloat16* __restrict__ dst)
{
    size_t i = ((size_t)blockIdx.x * 256 + threadIdx.x) * 4;   // over NL*256*2048
    int col   = (int)(i & 2047);
    int row   = (int)((i >> 11) & 255);
    int layer = (int)(i >> 19);
    union { __hip_bfloat16 h[4]; ushort4 u; } t;
    if (row < XPD_) {
        const float* s = src + ((size_t)layer * XPD_ + row) * 2048 + col;
        float4 v = *(const float4*)s;
        t.h[0] = __float2bfloat16(v.x);
        t.h[1] = __float2bfloat16(v.y);
        t.h[2] = __float2bfloat16(v.z);
        t.h[3] = __float2bfloat16(v.w);
    } else {
        t.h[0] = t.h[1] = t.h[2] = t.h[3] = __float2bfloat16(0.f);
    }
    *(ushort4*)(dst + i) = t.u;
}

// ---------------------------------------------------------------------------
// LayerNorm over DM=1024
// ---------------------------------------------------------------------------
template<typename OT>
__global__ __launch_bounds__(256)
void layernorm_k(const float* __restrict__ in, const float* __restrict__ w,
                 const float* __restrict__ b, OT* __restrict__ out,
                 int rstep, int rbase)
{
    __shared__ float red[8];
    int row_in = blockIdx.x * rstep + rbase;
    const float* p = in + (size_t)row_in * DM_;
    int tid = threadIdx.x;
    float4 x = *(const float4*)(p + tid * 4);
    float s  = x.x + x.y + x.z + x.w;
    float s2 = x.x * x.x + x.y * x.y + x.z * x.z + x.w * x.w;
    #pragma unroll
    for (int o = 32; o > 0; o >>= 1) {
        s  += __shfl_down(s, o);
        s2 += __shfl_down(s2, o);
    }
    if ((tid & 63) == 0) { red[tid >> 6] = s; red[4 + (tid >> 6)] = s2; }
    __syncthreads();
    float st  = red[0] + red[1] + red[2] + red[3];
    float s2t = red[4] + red[5] + red[6] + red[7];
    float m   = st * (1.f / DM_);
    float var = s2t * (1.f / DM_) - m * m;
    float rs  = rsqrtf(var + 1e-5f);
    float4 wv = *(const float4*)(w + tid * 4);
    float4 bv = *(const float4*)(b + tid * 4);
    float o0 = (x.x - m) * rs * wv.x + bv.x;
    float o1 = (x.y - m) * rs * wv.y + bv.y;
    float o2 = (x.z - m) * rs * wv.z + bv.z;
    float o3 = (x.w - m) * rs * wv.w + bv.w;
    size_t ob = (size_t)blockIdx.x * DM_ + tid * 4;
    if constexpr (sizeof(OT) == 4) {
        *(float4*)((float*)out + ob) = make_float4(o0, o1, o2, o3);
    } else {
        union { __hip_bfloat16 h[4]; ushort4 u; } t;
        t.h[0] = __float2bfloat16(o0);
        t.h[1] = __float2bfloat16(o1);
        t.h[2] = __float2bfloat16(o2);
        t.h[3] = __float2bfloat16(o3);
        *(ushort4*)((__hip_bfloat16*)out + ob) = t.u;
    }
}

// ---------------------------------------------------------------------------
// bf16 MFMA GEMM, 128x128 tile, BK=32, global_load_lds w16.
// MODE 0: full-K, C = A@Bw^T
// MODE 2: split-K partial -> Cp[z][M][ldc]
// MODE 3: split-K partial with epilogue col<Nb guard (B rows pre-padded)
// ---------------------------------------------------------------------------
template<int MODE>
__global__ __launch_bounds__(256)
void gemm_bf16(const __hip_bfloat16* __restrict__ A, int lda,
               const __hip_bfloat16* __restrict__ Bw, int ldb,
               float* __restrict__ C, int ldc, int Kp, int Nb)
{
    __shared__ __hip_bfloat16 As[128 * 32];
    __shared__ __hip_bfloat16 Bs[128 * 32];
    const int tid  = threadIdx.x;
    const int lane = tid & 63;
    const int wid  = tid >> 6;
    const int wm   = wid >> 1, wn = wid & 1;
    const int mbase = blockIdx.y * 128;
    const int nbase = blockIdx.x * 128;
    const int koff  = (MODE == 0) ? 0 : blockIdx.z * Kp;

    floatx4 acc[4][4] = {};

    const int f0 = tid * 16;
    const int r0 = f0 >> 6, c0 = f0 & 63;
    const int f1 = f0 + 4096;
    const int r1 = f1 >> 6, c1 = f1 & 63;

    const int fr = lane & 15;
    const int kq = (lane >> 4) * 8;

    for (int k0 = koff; k0 < koff + Kp; k0 += 32) {
        const char* Ag = (const char*)(A + (size_t)mbase * lda + k0);
        const char* Bg = (const char*)(Bw + (size_t)nbase * ldb + k0);
        async16(Ag + (size_t)r0 * lda * 2 + c0, (char*)As + f0);
        async16(Ag + (size_t)r1 * lda * 2 + c1, (char*)As + f1);
        async16(Bg + (size_t)r0 * ldb * 2 + c0, (char*)Bs + f0);
        async16(Bg + (size_t)r1 * ldb * 2 + c1, (char*)Bs + f1);
        __syncthreads();

        short8 af[4], bf[4];
        #pragma unroll
        for (int i = 0; i < 4; ++i) {
            int m = wm * 64 + i * 16 + fr;
            af[i] = *(const short8*)(As + m * 32 + kq);
            int n = wn * 64 + i * 16 + fr;
            bf[i] = *(const short8*)(Bs + n * 32 + kq);
        }
        #pragma unroll
        for (int i = 0; i < 4; ++i)
            #pragma unroll
            for (int j = 0; j < 4; ++j)
                acc[i][j] = __builtin_amdgcn_mfma_f32_16x16x32_bf16(
                    af[i], bf[j], acc[i][j], 0, 0, 0);
        __syncthreads();
    }

    const int cq = lane >> 4;
    size_t zoff = (MODE == 0) ? 0 : (size_t)blockIdx.z * (gridDim.y * 128) * ldc;
    #pragma unroll
    for (int i = 0; i < 4; ++i) {
        #pragma unroll
        for (int j = 0; j < 4; ++j) {
            int col = nbase + wn * 64 + j * 16 + fr;
            if (MODE == 3 && col >= Nb) continue;
            #pragma unroll
            for (int r = 0; r < 4; ++r) {
                int row = mbase + wm * 64 + i * 16 + cq * 4 + r;
                C[zoff + (size_t)row * ldc + col] = acc[i][j][r];
            }
        }
    }
}

// ---------------------------------------------------------------------------
// fp32 GEMM 64x64 tile (dt matmul): full-K, bias+softplus
// ---------------------------------------------------------------------------
template<bool BIAS, bool SOFTPLUS>
__global__ __launch_bounds__(256)
void gemm_nt(const float* __restrict__ A, int lda,
             const float* __restrict__ Bw, int ldb,
             float* __restrict__ C, int ldc,
             const float* __restrict__ bias, int Kdim)
{
    __shared__ float As[16][68];
    __shared__ float Bs[16][68];
    const int tid = threadIdx.x;
    const int tx = tid & 15, ty = tid >> 4;
    const int mbase = blockIdx.y * 64;
    const int nbase = blockIdx.x * 64;
    const int kk = tid & 15;
    const int r0 = tid >> 4;
    float acc[4][4] = {};

    for (int k0 = 0; k0 < Kdim; k0 += 16) {
        #pragma unroll
        for (int i = 0; i < 4; ++i) {
            int row = r0 + i * 16;
            As[kk][row] = A[(size_t)(mbase + row) * lda + k0 + kk];
            Bs[kk][row] = Bw[(size_t)(nbase + row) * ldb + k0 + kk];
        }
        __syncthreads();
        #pragma unroll
        for (int k = 0; k < 16; ++k) {
            const float4 av = *(const float4*)&As[k][ty * 4];
            const float4 bv = *(const float4*)&Bs[k][tx * 4];
            const float aa[4] = {av.x, av.y, av.z, av.w};
            const float bb[4] = {bv.x, bv.y, bv.z, bv.w};
            #pragma unroll
            for (int i = 0; i < 4; ++i)
                #pragma unroll
                for (int j = 0; j < 4; ++j)
                    acc[i][j] = fmaf(aa[i], bb[j], acc[i][j]);
        }
        __syncthreads();
    }

    #pragma unroll
    for (int i = 0; i < 4; ++i) {
        int row = mbase + ty * 4 + i;
        float vv[4];
        #pragma unroll
        for (int j = 0; j < 4; ++j) {
            float v = acc[i][j];
            if (BIAS) v += bias[nbase + tx * 4 + j];
            if (SOFTPLUS) v = (v > 20.f) ? v : log1pf(__expf(v));
            vv[j] = v;
        }
        *(float4*)&C[(size_t)row * ldc + nbase + tx * 4] =
            make_float4(vv[0], vv[1], vv[2], vv[3]);
    }
}

// ---------------------------------------------------------------------------
// Split-K reduction: dst[i] (+)= sum_z p[z*stride + i]
// ---------------------------------------------------------------------------
template<int PARTS, bool ACCUM>
__global__ __launch_bounds__(256)
void reduce_k(const float* __restrict__ p, float* __restrict__ dst, size_t stride)
{
    size_t i = ((size_t)blockIdx.x * 256 + threadIdx.x) * 4;
    float4 s = *(const float4*)(p + i);
    #pragma unroll
    for (int z = 1; z < PARTS; ++z) {
        float4 v = *(const float4*)(p + z * stride + i);
        s.x += v.x; s.y += v.y; s.z += v.z; s.w += v.w;
    }
    if (ACCUM) {
        float4 d = *(const float4*)(dst + i);
        s.x += d.x; s.y += d.y; s.z += d.z; s.w += d.w;
    }
    *(float4*)(dst + i) = s;
}

// ---------------------------------------------------------------------------
// Fused: h[row] += sum_z part[z][row]; then LayerNorm(h[row]) -> bf16 out.
// One block per row of DM=1024.
// ---------------------------------------------------------------------------
template<int PARTS>
__global__ __launch_bounds__(256)
void reduce_ln_k(const float* __restrict__ p, float* __restrict__ h,
                 const float* __restrict__ w, const float* __restrict__ b,
                 __hip_bfloat16* __restrict__ out, size_t stride)
{
    __shared__ float red[8];
    int tid = threadIdx.x;
    size_t base = (size_t)blockIdx.x * DM_ + tid * 4;
    float4 x = *(const float4*)(h + base);
    #pragma unroll
    for (int z = 0; z < PARTS; ++z) {
        float4 v = *(const float4*)(p + z * stride + base);
        x.x += v.x; x.y += v.y; x.z += v.z; x.w += v.w;
    }
    *(float4*)(h + base) = x;

    float s  = x.x + x.y + x.z + x.w;
    float s2 = x.x * x.x + x.y * x.y + x.z * x.z + x.w * x.w;
    #pragma unroll
    for (int o = 32; o > 0; o >>= 1) {
        s  += __shfl_down(s, o);
        s2 += __shfl_down(s2, o);
    }
    if ((tid & 63) == 0) { red[tid >> 6] = s; red[4 + (tid >> 6)] = s2; }
    __syncthreads();
    float st  = red[0] + red[1] + red[2] + red[3];
    float s2t = red[4] + red[5] + red[6] + red[7];
    float m   = st * (1.f / DM_);
    float var = s2t * (1.f / DM_) - m * m;
    float rs  = rsqrtf(var + 1e-5f);
    float4 wv = *(const float4*)(w + tid * 4);
    float4 bv = *(const float4*)(b + tid * 4);
    union { __hip_bfloat16 h[4]; ushort4 u; } t;
    t.h[0] = __float2bfloat16((x.x - m) * rs * wv.x + bv.x);
    t.h[1] = __float2bfloat16((x.y - m) * rs * wv.y + bv.y);
    t.h[2] = __float2bfloat16((x.z - m) * rs * wv.z + bv.z);
    t.h[3] = __float2bfloat16((x.w - m) * rs * wv.w + bv.w);
    *(ushort4*)(out + base) = t.u;
}

// ---------------------------------------------------------------------------
// Causal depthwise conv (K=4) + SiLU; writes fp32 xb and bf16 xb copy
// ---------------------------------------------------------------------------
__global__ __launch_bounds__(256)
void conv_silu(const float* __restrict__ xz, const float* __restrict__ cw,
               const float* __restrict__ cb, float* __restrict__ xb,
               __hip_bfloat16* __restrict__ xb_b)
{
    int idx = blockIdx.x * 256 + threadIdx.x;
    int d  = idx & (DI_ - 1);
    int bl = idx >> 11;
    int l  = bl & (L_ - 1);
    float s = cb[d];
    #pragma unroll
    for (int k = 0; k < 4; ++k) {
        int lk = l + k - 3;
        if (lk >= 0)
            s += cw[d * 4 + k] * xz[(size_t)(bl - l + lk) * (2 * DI_) + d];
    }
    float v = s / (1.f + __expf(-s));
    xb[idx] = v;
    xb_b[idx] = __float2bfloat16(v);
}

// ---------------------------------------------------------------------------
// SSM chunked scan
// ---------------------------------------------------------------------------
__global__ __launch_bounds__(256)
void ssm_pass1(const float* __restrict__ xb, const float* __restrict__ dlt,
               const float* __restrict__ xp, const float* __restrict__ Alog,
               float* __restrict__ Pc, float* __restrict__ Sc)
{
    int blk = blockIdx.x;
    int dgrp = blk & 7, c = (blk >> 3) & 7, b = blk >> 6;
    int d = (dgrp << 8) + threadIdx.x;
    __shared__ float Bsh[CHUNK_][N_];
    for (int i = threadIdx.x; i < CHUNK_ * N_; i += 256) {
        int t = i >> 4, n = i & 15;
        Bsh[t][n] = xp[(size_t)(b * L_ + c * CHUNK_ + t) * XPD_ + DTR_ + n];
    }
    __syncthreads();
    float a[N_], hn[N_], Pn[N_];
    #pragma unroll
    for (int n = 0; n < N_; ++n) {
        a[n] = -__expf(Alog[d * N_ + n]);
        hn[n] = 0.f; Pn[n] = 1.f;
    }
    for (int t = 0; t < CHUNK_; ++t) {
        size_t off = (size_t)(b * L_ + c * CHUNK_ + t) * DI_ + d;
        float dt = dlt[off], xv = xb[off];
        float dx = dt * xv;
        #pragma unroll
        for (int n = 0; n < N_; ++n) {
            float dA = __expf(dt * a[n]);
            hn[n] = dA * hn[n] + dx * Bsh[t][n];
            Pn[n] *= dA;
        }
    }
    #pragma unroll
    for (int n = 0; n < N_; ++n) {
        size_t o = ((size_t)((b * NC_ + c) * N_ + n)) * DI_ + d;
        Pc[o] = Pn[n]; Sc[o] = hn[n];
    }
}

__global__ __launch_bounds__(256)
void ssm_scan(const float* __restrict__ Pc, const float* __restrict__ Sc,
              float* __restrict__ hstart)
{
    int idx = blockIdx.x * 256 + threadIdx.x;
    int d = idx & (DI_ - 1);
    int bn = idx >> 11;
    int n = bn & 15, b = bn >> 4;
    float h = 0.f;
    for (int c = 0; c < NC_; ++c) {
        size_t o = ((size_t)((b * NC_ + c) * N_ + n)) * DI_ + d;
        hstart[o] = h;
        h = Pc[o] * h + Sc[o];
    }
}

__global__ __launch_bounds__(256)
void ssm_pass2(const float* __restrict__ xb, const float* __restrict__ dlt,
               const float* __restrict__ xp, const float* __restrict__ Alog,
               const float* __restrict__ Dp, const float* __restrict__ xz,
               const float* __restrict__ hstart, __hip_bfloat16* __restrict__ yout)
{
    int blk = blockIdx.x;
    int dgrp = blk & 7, c = (blk >> 3) & 7, b = blk >> 6;
    int d = (dgrp << 8) + threadIdx.x;
    __shared__ float Bsh[CHUNK_][N_], Csh[CHUNK_][N_];
    for (int i = threadIdx.x; i < CHUNK_ * 2 * N_; i += 256) {
        int t = i >> 5, j = i & 31;
        float v = xp[(size_t)(b * L_ + c * CHUNK_ + t) * XPD_ + DTR_ + j];
        if (j < 16) Bsh[t][j] = v; else Csh[t][j - 16] = v;
    }
    __syncthreads();
    float a[N_], hn[N_];
    #pragma unroll
    for (int n = 0; n < N_; ++n) {
        a[n] = -__expf(Alog[d * N_ + n]);
        hn[n] = hstart[((size_t)((b * NC_ + c) * N_ + n)) * DI_ + d];
    }
    float dpv = Dp[d];
    for (int t = 0; t < CHUNK_; ++t) {
        int l = c * CHUNK_ + t;
        size_t off = (size_t)(b * L_ + l) * DI_ + d;
        float dt = dlt[off], xv = xb[off];
        float dx = dt * xv;
        float yv = 0.f;
        #pragma unroll
        for (int n = 0; n < N_; ++n) {
            float dA = __expf(dt * a[n]);
            hn[n] = dA * hn[n] + dx * Bsh[t][n];
            yv += hn[n] * Csh[t][n];
        }
        yv += xv * dpv;
        float z = xz[(size_t)(b * L_ + l) * (2 * DI_) + DI_ + d];
        yout[off] = __float2bfloat16(yv * z / (1.f + __expf(-z)));
    }
}

// ---------------------------------------------------------------------------
// Head
// ---------------------------------------------------------------------------
__global__ __launch_bounds__(256)
void head_k(const float* __restrict__ hln, const float* __restrict__ hw,
            float* __restrict__ out)
{
    __shared__ float red[4];
    int b = blockIdx.x / P_;
    int p = blockIdx.x % P_;
    int tid = threadIdx.x;
    const float* av = hln + (size_t)b * DM_;
    const float* wv = hw + (size_t)p * DM_;
    float4 xa = *(const float4*)(av + tid * 4);
    float4 xw = *(const float4*)(wv + tid * 4);
    float s = xa.x * xw.x + xa.y * xw.y + xa.z * xw.z + xa.w * xw.w;
    #pragma unroll
    for (int o = 32; o > 0; o >>= 1) s += __shfl_down(s, o);
    if ((tid & 63) == 0) red[tid >> 6] = s;
    __syncthreads();
    if (tid == 0) out[blockIdx.x] = red[0] + red[1] + red[2] + red[3];
}

// ---------------------------------------------------------------------------
extern "C" void kernel_launch(void* const* d_in, const int* in_sizes, int n_in,
                              void* d_out, int out_size, void* d_ws, size_t ws_size,
                              hipStream_t stream)
{
    const int*   tokens     = (const int*)  d_in[0];
    const float* tok_emb    = (const float*)d_in[1];
    const float* pos_emb    = (const float*)d_in[2];
    const float* ln_w       = (const float*)d_in[3];
    const float* ln_b       = (const float*)d_in[4];
    const float* in_proj_w  = (const float*)d_in[5];
    const float* conv_w     = (const float*)d_in[6];
    const float* conv_b     = (const float*)d_in[7];
    const float* xproj_w    = (const float*)d_in[8];
    const float* dt_w       = (const float*)d_in[9];
    const float* dt_b       = (const float*)d_in[10];
    const float* A_log      = (const float*)d_in[11];
    const float* D_param    = (const float*)d_in[12];
    const float* out_proj_w = (const float*)d_in[13];
    const float* fnorm_w    = (const float*)d_in[14];
    const float* fnorm_b    = (const float*)d_in[15];
    const float* head_w     = (const float*)d_in[16];
    float* out = (float*)d_out;
    float* ws  = (float*)d_ws;

    // fp32 workspace (floats)
    float* h    = ws;                  // B*L*DM    = 2,097,152
    float* xz   = h    + 2097152;      // B*L*2DI   = 8,388,608
    float* xb   = xz   + 8388608;      // B*L*DI    = 4,194,304
    float* xp   = xb   + 4194304;      // B*L*XPD   =   327,680
    float* dlt  = xp   + 327680;       // B*L*DI    = 4,194,304
    float* Pc   = dlt  + 4194304;      // B*NC*N*DI = 2,097,152
    float* Sc   = Pc   + 2097152;      // 2,097,152
    float* hst  = Sc   + 2097152;      // 2,097,152
    float* hfin = hst  + 2097152;      // B*DM      = 8,192
    // bf16 workspace
    __hip_bfloat16* bfbase = (__hip_bfloat16*)(hfin + 8192);
    __hip_bfloat16* xln_b = bfbase;              // B*L*DM  = 2,097,152 el
    __hip_bfloat16* y_b   = xln_b + 2097152;     // B*L*DI  = 4,194,304 el
    __hip_bfloat16* xb_b  = y_b   + 4194304;     // B*L*DI  = 4,194,304 el
    __hip_bfloat16* ipw_b = xb_b  + 4194304;     // NL*2DI*DM = 16,777,216 el
    __hip_bfloat16* opw_b = ipw_b + 16777216;    // NL*DM*DI  =  8,388,608 el
    __hip_bfloat16* xpw_b = opw_b + 8388608;     // NL*256*2048 = 2,097,152 el
    // split-K partials (aliased):
    //  part_xp: 8 x 2048 x 160 = 2,621,440 fl -> aliases Pc+Sc (dead until pass1)
    float* part_xp = Pc;
    //  part_h: 4 x 2048 x 1024 = 8,388,608 fl -> aliases xz (dead after pass2)
    float* part_h = xz;

    // ---- upfront: all weights to bf16 (once per call, outside layer loop)
    f32_to_bf16_k<<<NL_ * 2 * DI_ * DM_ / 1024, 256, 0, stream>>>(in_proj_w, ipw_b);
    f32_to_bf16_k<<<NL_ * DM_ * DI_ / 1024, 256, 0, stream>>>(out_proj_w, opw_b);
    conv_xpw_k<<<NL_ * 256 * 2048 / 1024, 256, 0, stream>>>(xproj_w, xpw_b);

    embed_k<<<B_ * L_ * DM_ / 256, 256, 0, stream>>>(tokens, tok_emb, pos_emb, h);
    // LN for layer 0
    layernorm_k<__hip_bfloat16><<<B_ * L_, 256, 0, stream>>>(
        h, ln_w, ln_b, xln_b, 1, 0);

    for (int li = 0; li < NL_; ++li) {
        // xz = x @ in_proj_w^T   (2048 x 4096, K=1024)  [bf16 MFMA]
        gemm_bf16<0><<<dim3(2 * DI_ / 128, B_ * L_ / 128), 256, 0, stream>>>(
            xln_b, DM_, ipw_b + (size_t)li * 2 * DI_ * DM_, DM_,
            xz, 2 * DI_, DM_, 0);

        // x_branch = silu(conv(xz[...,:DI]))  -> fp32 + bf16
        conv_silu<<<B_ * L_ * DI_ / 256, 256, 0, stream>>>(
            xz, conv_w + li * DI_ * K_, conv_b + li * DI_, xb, xb_b);

        // xp = x_branch @ xproj_w^T  (2048 x 160, K=2048) [bf16 MFMA splitK-8]
        gemm_bf16<3><<<dim3(2, B_ * L_ / 128, 8), 256, 0, stream>>>(
            xb_b, DI_, xpw_b + (size_t)li * 256 * 2048, DI_,
            part_xp, XPD_, DI_ / 8, XPD_);
        reduce_k<8, false><<<B_ * L_ * XPD_ / 1024, 256, 0, stream>>>(
            part_xp, xp, (size_t)B_ * L_ * XPD_);

        // delta = softplus(dt_r @ dt_w^T + dt_b)  (2048 x 2048, K=128) [fp32]
        gemm_nt<true, true><<<dim3(DI_ / 64, B_ * L_ / 64), 256, 0, stream>>>(
            xp, XPD_, dt_w + (size_t)li * DI_ * DTR_, DTR_,
            dlt, DI_, dt_b + li * DI_, DTR_);

        // chunked selective scan
        ssm_pass1<<<B_ * NC_ * (DI_ / 256), 256, 0, stream>>>(
            xb, dlt, xp, A_log + li * DI_ * N_, Pc, Sc);
        ssm_scan<<<B_ * N_ * DI_ / 256, 256, 0, stream>>>(Pc, Sc, hst);
        ssm_pass2<<<B_ * NC_ * (DI_ / 256), 256, 0, stream>>>(
            xb, dlt, xp, A_log + li * DI_ * N_, D_param + li * DI_, xz, hst, y_b);

        // h += y @ out_proj_w^T  (2048 x 1024, K=2048) [bf16 MFMA splitK-4]
        gemm_bf16<2><<<dim3(DM_ / 128, B_ * L_ / 128, 4), 256, 0, stream>>>(
            y_b, DI_, opw_b + (size_t)li * DM_ * DI_, DI_,
            part_h, DM_, DI_ / 4, 0);

        if (li < NL_ - 1) {
            // fused: h += parts; xln_b = LN(h) with next layer's params
            reduce_ln_k<4><<<B_ * L_, 256, 0, stream>>>(
                part_h, h, ln_w + (li + 1) * DM_, ln_b + (li + 1) * DM_,
                xln_b, (size_t)B_ * L_ * DM_);
        } else {
            reduce_k<4, true><<<B_ * L_ * DM_ / 1024, 256, 0, stream>>>(
                part_h, h, (size_t)B_ * L_ * DM_);
        }
    }

    // final LN on last token of each batch
    layernorm_k<float><<<B_, 256, 0, stream>>>(h, fnorm_w, fnorm_b, hfin, L_, L_ - 1);
    // logits
    head_k<<<B_ * P_, 256, 0, stream>>>(hfin, head_w, out);
}

// Round 5
// 923.315 us; speedup vs baseline: 3.3011x; 1.0314x over previous
//
#include <hip/hip_runtime.h>
#include <hip/hip_bf16.h>
#include <cstdint>
#include <cstddef>

#define B_    8
#define L_    256
#define DM_   1024
#define DI_   2048
#define N_    16
#define K_    4
#define NL_   4
#define DTR_  128
#define P_    97
#define XPD_  160   // DTR + 2N
#define CHUNK_ 32
#define NC_   8     // L / CHUNK

typedef __attribute__((ext_vector_type(8))) short short8;
typedef __attribute__((ext_vector_type(4))) float floatx4;

__device__ __forceinline__ void async16(const void* g, void* l)
{
    __builtin_amdgcn_global_load_lds(
        (const __attribute__((address_space(1))) void*)g,
        (__attribute__((address_space(3))) void*)l,
        16, 0, 0);
}

__device__ __forceinline__ void cvt4(const float* s, __hip_bfloat16* d)
{
    float4 v = *(const float4*)s;
    union { __hip_bfloat16 h[4]; ushort4 u; } t;
    t.h[0] = __float2bfloat16(v.x);
    t.h[1] = __float2bfloat16(v.y);
    t.h[2] = __float2bfloat16(v.z);
    t.h[3] = __float2bfloat16(v.w);
    *(ushort4*)d = t.u;
}

// ---------------------------------------------------------------------------
// One-shot conversion of ALL weights fp32->bf16 (xproj padded 160->256 rows)
// blocks: [0,16384) ipw | [16384,24576) opw | [24576,25600) dtw | rest xpw
// ---------------------------------------------------------------------------
__global__ __launch_bounds__(256)
void wconv_all(const float* __restrict__ ipw, const float* __restrict__ opw,
               const float* __restrict__ dtw, const float* __restrict__ xpw,
               __hip_bfloat16* __restrict__ ipb, __hip_bfloat16* __restrict__ opb,
               __hip_bfloat16* __restrict__ dtb, __hip_bfloat16* __restrict__ xpb)
{
    int blk = blockIdx.x;
    if (blk < 16384) {
        size_t i = ((size_t)blk * 256 + threadIdx.x) * 4;
        cvt4(ipw + i, ipb + i);
    } else if (blk < 24576) {
        size_t i = ((size_t)(blk - 16384) * 256 + threadIdx.x) * 4;
        cvt4(opw + i, opb + i);
    } else if (blk < 25600) {
        size_t i = ((size_t)(blk - 24576) * 256 + threadIdx.x) * 4;
        cvt4(dtw + i, dtb + i);
    } else {
        size_t i = ((size_t)(blk - 25600) * 256 + threadIdx.x) * 4; // NL*256*2048
        int col   = (int)(i & 2047);
        int row   = (int)((i >> 11) & 255);
        int layer = (int)(i >> 19);
        if (row < XPD_) {
            cvt4(xpw + ((size_t)layer * XPD_ + row) * 2048 + col, xpb + i);
        } else {
            union { __hip_bfloat16 h[4]; ushort4 u; } t;
            t.h[0] = t.h[1] = t.h[2] = t.h[3] = __float2bfloat16(0.f);
            *(ushort4*)(xpb + i) = t.u;
        }
    }
}

// ---------------------------------------------------------------------------
// Fused embedding + layer-0 LayerNorm. One block per (b,l) row.
// ---------------------------------------------------------------------------
__global__ __launch_bounds__(256)
void embed_ln_k(const int* __restrict__ tokens, const float* __restrict__ te,
                const float* __restrict__ pe, const float* __restrict__ lw,
                const float* __restrict__ lb, float* __restrict__ h,
                __hip_bfloat16* __restrict__ xout)
{
    __shared__ float red[8];
    int bl = blockIdx.x;
    int l  = bl & (L_ - 1);
    int tok = tokens[bl];
    int tid = threadIdx.x;
    float4 a = *(const float4*)(te + (size_t)tok * DM_ + tid * 4);
    float4 p = *(const float4*)(pe + (size_t)l * DM_ + tid * 4);
    float4 x = make_float4(a.x + p.x, a.y + p.y, a.z + p.z, a.w + p.w);
    size_t base = (size_t)bl * DM_ + tid * 4;
    *(float4*)(h + base) = x;

    float s  = x.x + x.y + x.z + x.w;
    float s2 = x.x * x.x + x.y * x.y + x.z * x.z + x.w * x.w;
    #pragma unroll
    for (int o = 32; o > 0; o >>= 1) {
        s  += __shfl_down(s, o);
        s2 += __shfl_down(s2, o);
    }
    if ((tid & 63) == 0) { red[tid >> 6] = s; red[4 + (tid >> 6)] = s2; }
    __syncthreads();
    float st  = red[0] + red[1] + red[2] + red[3];
    float s2t = red[4] + red[5] + red[6] + red[7];
    float m   = st * (1.f / DM_);
    float var = s2t * (1.f / DM_) - m * m;
    float rs  = rsqrtf(var + 1e-5f);
    float4 wv = *(const float4*)(lw + tid * 4);
    float4 bv = *(const float4*)(lb + tid * 4);
    union { __hip_bfloat16 h[4]; ushort4 u; } t;
    t.h[0] = __float2bfloat16((x.x - m) * rs * wv.x + bv.x);
    t.h[1] = __float2bfloat16((x.y - m) * rs * wv.y + bv.y);
    t.h[2] = __float2bfloat16((x.z - m) * rs * wv.z + bv.z);
    t.h[3] = __float2bfloat16((x.w - m) * rs * wv.w + bv.w);
    *(ushort4*)(xout + base) = t.u;
}

// ---------------------------------------------------------------------------
// bf16 MFMA GEMM, 128x128 tile, BK=32, global_load_lds w16.
// MODE 0: full-K, C = A@Bw^T
// MODE 2: split-K partial -> Cp[z][M][ldc]
// MODE 3: split-K partial with epilogue col<Nb guard (B rows pre-padded)
// MODE 4: full-K with bias + softplus epilogue (dt matmul)
// ---------------------------------------------------------------------------
template<int MODE>
__global__ __launch_bounds__(256)
void gemm_bf16(const __hip_bfloat16* __restrict__ A, int lda,
               const __hip_bfloat16* __restrict__ Bw, int ldb,
               float* __restrict__ C, int ldc, int Kp, int Nb,
               const float* __restrict__ bias)
{
    __shared__ __hip_bfloat16 As[128 * 32];
    __shared__ __hip_bfloat16 Bs[128 * 32];
    const int tid  = threadIdx.x;
    const int lane = tid & 63;
    const int wid  = tid >> 6;
    const int wm   = wid >> 1, wn = wid & 1;
    const int mbase = blockIdx.y * 128;
    const int nbase = blockIdx.x * 128;
    const int koff  = (MODE == 2 || MODE == 3) ? blockIdx.z * Kp : 0;

    floatx4 acc[4][4] = {};

    const int f0 = tid * 16;
    const int r0 = f0 >> 6, c0 = f0 & 63;
    const int f1 = f0 + 4096;
    const int r1 = f1 >> 6, c1 = f1 & 63;

    const int fr = lane & 15;
    const int kq = (lane >> 4) * 8;

    for (int k0 = koff; k0 < koff + Kp; k0 += 32) {
        const char* Ag = (const char*)(A + (size_t)mbase * lda + k0);
        const char* Bg = (const char*)(Bw + (size_t)nbase * ldb + k0);
        async16(Ag + (size_t)r0 * lda * 2 + c0, (char*)As + f0);
        async16(Ag + (size_t)r1 * lda * 2 + c1, (char*)As + f1);
        async16(Bg + (size_t)r0 * ldb * 2 + c0, (char*)Bs + f0);
        async16(Bg + (size_t)r1 * ldb * 2 + c1, (char*)Bs + f1);
        __syncthreads();

        short8 af[4], bf[4];
        #pragma unroll
        for (int i = 0; i < 4; ++i) {
            int m = wm * 64 + i * 16 + fr;
            af[i] = *(const short8*)(As + m * 32 + kq);
            int n = wn * 64 + i * 16 + fr;
            bf[i] = *(const short8*)(Bs + n * 32 + kq);
        }
        #pragma unroll
        for (int i = 0; i < 4; ++i)
            #pragma unroll
            for (int j = 0; j < 4; ++j)
                acc[i][j] = __builtin_amdgcn_mfma_f32_16x16x32_bf16(
                    af[i], bf[j], acc[i][j], 0, 0, 0);
        __syncthreads();
    }

    const int cq = lane >> 4;
    size_t zoff = (MODE == 2 || MODE == 3)
                ? (size_t)blockIdx.z * (gridDim.y * 128) * ldc : 0;
    #pragma unroll
    for (int i = 0; i < 4; ++i) {
        #pragma unroll
        for (int j = 0; j < 4; ++j) {
            int col = nbase + wn * 64 + j * 16 + fr;
            if (MODE == 3 && col >= Nb) continue;
            float bv = (MODE == 4) ? bias[col] : 0.f;
            #pragma unroll
            for (int r = 0; r < 4; ++r) {
                int row = mbase + wm * 64 + i * 16 + cq * 4 + r;
                float v = acc[i][j][r];
                if (MODE == 4) {
                    v += bv;
                    v = (v > 20.f) ? v : log1pf(__expf(v));
                }
                C[zoff + (size_t)row * ldc + col] = v;
            }
        }
    }
}

// ---------------------------------------------------------------------------
// Split-K reduction: dst[i] (+)= sum_z p[z*stride + i]
// ---------------------------------------------------------------------------
template<int PARTS, bool ACCUM>
__global__ __launch_bounds__(256)
void reduce_k(const float* __restrict__ p, float* __restrict__ dst, size_t stride)
{
    size_t i = ((size_t)blockIdx.x * 256 + threadIdx.x) * 4;
    float4 s = *(const float4*)(p + i);
    #pragma unroll
    for (int z = 1; z < PARTS; ++z) {
        float4 v = *(const float4*)(p + z * stride + i);
        s.x += v.x; s.y += v.y; s.z += v.z; s.w += v.w;
    }
    if (ACCUM) {
        float4 d = *(const float4*)(dst + i);
        s.x += d.x; s.y += d.y; s.z += d.z; s.w += d.w;
    }
    *(float4*)(dst + i) = s;
}

// Split-K reduce for xp: emit fp32 xp AND bf16 xp_b
template<int PARTS>
__global__ __launch_bounds__(256)
void reduce_xp_k(const float* __restrict__ p, float* __restrict__ dst,
                 __hip_bfloat16* __restrict__ dst_b, size_t stride)
{
    size_t i = ((size_t)blockIdx.x * 256 + threadIdx.x) * 4;
    float4 s = *(const float4*)(p + i);
    #pragma unroll
    for (int z = 1; z < PARTS; ++z) {
        float4 v = *(const float4*)(p + z * stride + i);
        s.x += v.x; s.y += v.y; s.z += v.z; s.w += v.w;
    }
    *(float4*)(dst + i) = s;
    union { __hip_bfloat16 h[4]; ushort4 u; } t;
    t.h[0] = __float2bfloat16(s.x);
    t.h[1] = __float2bfloat16(s.y);
    t.h[2] = __float2bfloat16(s.z);
    t.h[3] = __float2bfloat16(s.w);
    *(ushort4*)(dst_b + i) = t.u;
}

// ---------------------------------------------------------------------------
// Fused: h[row] += sum_z part[z][row]; then LayerNorm(h[row]) -> bf16 out.
// ---------------------------------------------------------------------------
template<int PARTS>
__global__ __launch_bounds__(256)
void reduce_ln_k(const float* __restrict__ p, float* __restrict__ h,
                 const float* __restrict__ w, const float* __restrict__ b,
                 __hip_bfloat16* __restrict__ out, size_t stride)
{
    __shared__ float red[8];
    int tid = threadIdx.x;
    size_t base = (size_t)blockIdx.x * DM_ + tid * 4;
    float4 x = *(const float4*)(h + base);
    #pragma unroll
    for (int z = 0; z < PARTS; ++z) {
        float4 v = *(const float4*)(p + z * stride + base);
        x.x += v.x; x.y += v.y; x.z += v.z; x.w += v.w;
    }
    *(float4*)(h + base) = x;

    float s  = x.x + x.y + x.z + x.w;
    float s2 = x.x * x.x + x.y * x.y + x.z * x.z + x.w * x.w;
    #pragma unroll
    for (int o = 32; o > 0; o >>= 1) {
        s  += __shfl_down(s, o);
        s2 += __shfl_down(s2, o);
    }
    if ((tid & 63) == 0) { red[tid >> 6] = s; red[4 + (tid >> 6)] = s2; }
    __syncthreads();
    float st  = red[0] + red[1] + red[2] + red[3];
    float s2t = red[4] + red[5] + red[6] + red[7];
    float m   = st * (1.f / DM_);
    float var = s2t * (1.f / DM_) - m * m;
    float rs  = rsqrtf(var + 1e-5f);
    float4 wv = *(const float4*)(w + tid * 4);
    float4 bv = *(const float4*)(b + tid * 4);
    union { __hip_bfloat16 h[4]; ushort4 u; } t;
    t.h[0] = __float2bfloat16((x.x - m) * rs * wv.x + bv.x);
    t.h[1] = __float2bfloat16((x.y - m) * rs * wv.y + bv.y);
    t.h[2] = __float2bfloat16((x.z - m) * rs * wv.z + bv.z);
    t.h[3] = __float2bfloat16((x.w - m) * rs * wv.w + bv.w);
    *(ushort4*)(out + base) = t.u;
}

// ---------------------------------------------------------------------------
// Causal depthwise conv (K=4) + SiLU -> bf16 only
// ---------------------------------------------------------------------------
__global__ __launch_bounds__(256)
void conv_silu(const float* __restrict__ xz, const float* __restrict__ cw,
               const float* __restrict__ cb, __hip_bfloat16* __restrict__ xb_b)
{
    int idx = blockIdx.x * 256 + threadIdx.x;
    int d  = idx & (DI_ - 1);
    int bl = idx >> 11;
    int l  = bl & (L_ - 1);
    float s = cb[d];
    #pragma unroll
    for (int k = 0; k < 4; ++k) {
        int lk = l + k - 3;
        if (lk >= 0)
            s += cw[d * 4 + k] * xz[(size_t)(bl - l + lk) * (2 * DI_) + d];
    }
    float v = s / (1.f + __expf(-s));
    xb_b[idx] = __float2bfloat16(v);
}

// ---------------------------------------------------------------------------
// SSM chunked scan (x read as bf16)
// ---------------------------------------------------------------------------
__global__ __launch_bounds__(256)
void ssm_pass1(const __hip_bfloat16* __restrict__ xb_b,
               const float* __restrict__ dlt,
               const float* __restrict__ xp, const float* __restrict__ Alog,
               float* __restrict__ Pc, float* __restrict__ Sc)
{
    int blk = blockIdx.x;
    int dgrp = blk & 7, c = (blk >> 3) & 7, b = blk >> 6;
    int d = (dgrp << 8) + threadIdx.x;
    __shared__ float Bsh[CHUNK_][N_];
    for (int i = threadIdx.x; i < CHUNK_ * N_; i += 256) {
        int t = i >> 4, n = i & 15;
        Bsh[t][n] = xp[(size_t)(b * L_ + c * CHUNK_ + t) * XPD_ + DTR_ + n];
    }
    __syncthreads();
    float a[N_], hn[N_], Pn[N_];
    #pragma unroll
    for (int n = 0; n < N_; ++n) {
        a[n] = -__expf(Alog[d * N_ + n]);
        hn[n] = 0.f; Pn[n] = 1.f;
    }
    for (int t = 0; t < CHUNK_; ++t) {
        size_t off = (size_t)(b * L_ + c * CHUNK_ + t) * DI_ + d;
        float dt = dlt[off];
        float xv = __bfloat162float(xb_b[off]);
        float dx = dt * xv;
        #pragma unroll
        for (int n = 0; n < N_; ++n) {
            float dA = __expf(dt * a[n]);
            hn[n] = dA * hn[n] + dx * Bsh[t][n];
            Pn[n] *= dA;
        }
    }
    #pragma unroll
    for (int n = 0; n < N_; ++n) {
        size_t o = ((size_t)((b * NC_ + c) * N_ + n)) * DI_ + d;
        Pc[o] = Pn[n]; Sc[o] = hn[n];
    }
}

__global__ __launch_bounds__(256)
void ssm_scan(const float* __restrict__ Pc, const float* __restrict__ Sc,
              float* __restrict__ hstart)
{
    int idx = blockIdx.x * 256 + threadIdx.x;
    int d = idx & (DI_ - 1);
    int bn = idx >> 11;
    int n = bn & 15, b = bn >> 4;
    float h = 0.f;
    for (int c = 0; c < NC_; ++c) {
        size_t o = ((size_t)((b * NC_ + c) * N_ + n)) * DI_ + d;
        hstart[o] = h;
        h = Pc[o] * h + Sc[o];
    }
}

__global__ __launch_bounds__(256)
void ssm_pass2(const __hip_bfloat16* __restrict__ xb_b,
               const float* __restrict__ dlt,
               const float* __restrict__ xp, const float* __restrict__ Alog,
               const float* __restrict__ Dp, const float* __restrict__ xz,
               const float* __restrict__ hstart, __hip_bfloat16* __restrict__ yout)
{
    int blk = blockIdx.x;
    int dgrp = blk & 7, c = (blk >> 3) & 7, b = blk >> 6;
    int d = (dgrp << 8) + threadIdx.x;
    __shared__ float Bsh[CHUNK_][N_], Csh[CHUNK_][N_];
    for (int i = threadIdx.x; i < CHUNK_ * 2 * N_; i += 256) {
        int t = i >> 5, j = i & 31;
        float v = xp[(size_t)(b * L_ + c * CHUNK_ + t) * XPD_ + DTR_ + j];
        if (j < 16) Bsh[t][j] = v; else Csh[t][j - 16] = v;
    }
    __syncthreads();
    float a[N_], hn[N_];
    #pragma unroll
    for (int n = 0; n < N_; ++n) {
        a[n] = -__expf(Alog[d * N_ + n]);
        hn[n] = hstart[((size_t)((b * NC_ + c) * N_ + n)) * DI_ + d];
    }
    float dpv = Dp[d];
    for (int t = 0; t < CHUNK_; ++t) {
        int l = c * CHUNK_ + t;
        size_t off = (size_t)(b * L_ + l) * DI_ + d;
        float dt = dlt[off];
        float xv = __bfloat162float(xb_b[off]);
        float dx = dt * xv;
        float yv = 0.f;
        #pragma unroll
        for (int n = 0; n < N_; ++n) {
            float dA = __expf(dt * a[n]);
            hn[n] = dA * hn[n] + dx * Bsh[t][n];
            yv += hn[n] * Csh[t][n];
        }
        yv += xv * dpv;
        float z = xz[(size_t)(b * L_ + l) * (2 * DI_) + DI_ + d];
        yout[off] = __float2bfloat16(yv * z / (1.f + __expf(-z)));
    }
}

// ---------------------------------------------------------------------------
// Fused final LayerNorm + head. out[b,p] = dot(LN(h[b,L-1]), head_w[p]).
// Expanded: out = rs*(t1 - m*t2) + t3, t1=Σx·w·hw, t2=Σw·hw, t3=Σb·hw.
// ---------------------------------------------------------------------------
__global__ __launch_bounds__(256)
void head_ln_k(const float* __restrict__ h, const float* __restrict__ fw,
               const float* __restrict__ fb, const float* __restrict__ hw,
               float* __restrict__ out)
{
    __shared__ float red[4][5];
    int b = blockIdx.x / P_;
    int p = blockIdx.x % P_;
    int tid = threadIdx.x;
    const float* row = h + ((size_t)(b * L_ + L_ - 1)) * DM_;
    float4 x  = *(const float4*)(row + tid * 4);
    float4 w4 = *(const float4*)(fw + tid * 4);
    float4 b4 = *(const float4*)(fb + tid * 4);
    float4 g4 = *(const float4*)(hw + (size_t)p * DM_ + tid * 4);
    float s  = x.x + x.y + x.z + x.w;
    float s2 = x.x * x.x + x.y * x.y + x.z * x.z + x.w * x.w;
    float t1 = x.x * w4.x * g4.x + x.y * w4.y * g4.y + x.z * w4.z * g4.z + x.w * w4.w * g4.w;
    float t2 = w4.x * g4.x + w4.y * g4.y + w4.z * g4.z + w4.w * g4.w;
    float t3 = b4.x * g4.x + b4.y * g4.y + b4.z * g4.z + b4.w * g4.w;
    #pragma unroll
    for (int o = 32; o > 0; o >>= 1) {
        s  += __shfl_down(s, o);
        s2 += __shfl_down(s2, o);
        t1 += __shfl_down(t1, o);
        t2 += __shfl_down(t2, o);
        t3 += __shfl_down(t3, o);
    }
    if ((tid & 63) == 0) {
        int w = tid >> 6;
        red[w][0] = s; red[w][1] = s2; red[w][2] = t1; red[w][3] = t2; red[w][4] = t3;
    }
    __syncthreads();
    if (tid == 0) {
        float st  = red[0][0] + red[1][0] + red[2][0] + red[3][0];
        float s2t = red[0][1] + red[1][1] + red[2][1] + red[3][1];
        float t1t = red[0][2] + red[1][2] + red[2][2] + red[3][2];
        float t2t = red[0][3] + red[1][3] + red[2][3] + red[3][3];
        float t3t = red[0][4] + red[1][4] + red[2][4] + red[3][4];
        float m   = st * (1.f / DM_);
        float var = s2t * (1.f / DM_) - m * m;
        float rs  = rsqrtf(var + 1e-5f);
        out[blockIdx.x] = rs * (t1t - m * t2t) + t3t;
    }
}

// ---------------------------------------------------------------------------
extern "C" void kernel_launch(void* const* d_in, const int* in_sizes, int n_in,
                              void* d_out, int out_size, void* d_ws, size_t ws_size,
                              hipStream_t stream)
{
    const int*   tokens     = (const int*)  d_in[0];
    const float* tok_emb    = (const float*)d_in[1];
    const float* pos_emb    = (const float*)d_in[2];
    const float* ln_w       = (const float*)d_in[3];
    const float* ln_b       = (const float*)d_in[4];
    const float* in_proj_w  = (const float*)d_in[5];
    const float* conv_w     = (const float*)d_in[6];
    const float* conv_b     = (const float*)d_in[7];
    const float* xproj_w    = (const float*)d_in[8];
    const float* dt_w       = (const float*)d_in[9];
    const float* dt_b       = (const float*)d_in[10];
    const float* A_log      = (const float*)d_in[11];
    const float* D_param    = (const float*)d_in[12];
    const float* out_proj_w = (const float*)d_in[13];
    const float* fnorm_w    = (const float*)d_in[14];
    const float* fnorm_b    = (const float*)d_in[15];
    const float* head_w     = (const float*)d_in[16];
    float* out = (float*)d_out;
    float* ws  = (float*)d_ws;

    // fp32 workspace (floats)
    float* h    = ws;                  // B*L*DM    = 2,097,152
    float* xz   = h    + 2097152;      // B*L*2DI   = 8,388,608
    float* aux  = xz   + 8388608;      // 4,194,304 (bf16 xp_b / dtw_b live here)
    float* xp   = aux  + 4194304;      // B*L*XPD   =   327,680
    float* dlt  = xp   + 327680;       // B*L*DI    = 4,194,304
    float* Pc   = dlt  + 4194304;      // B*NC*N*DI = 2,097,152
    float* Sc   = Pc   + 2097152;      // 2,097,152
    float* hst  = Sc   + 2097152;      // 2,097,152
    // bf16 aliases inside aux (688,128 floats used of 4,194,304)
    __hip_bfloat16* xp_b  = (__hip_bfloat16*)aux;          // B*L*XPD = 327,680 el
    __hip_bfloat16* dtw_b = xp_b + 327680;                 // NL*DI*DTR = 1,048,576 el
    // bf16 workspace after fp32 region
    __hip_bfloat16* bfbase = (__hip_bfloat16*)(hst + 2097152);
    __hip_bfloat16* xln_b = bfbase;              // B*L*DM  = 2,097,152 el
    __hip_bfloat16* y_b   = xln_b + 2097152;     // B*L*DI  = 4,194,304 el
    __hip_bfloat16* xb_b  = y_b   + 4194304;     // B*L*DI  = 4,194,304 el
    __hip_bfloat16* ipw_b = xb_b  + 4194304;     // NL*2DI*DM = 16,777,216 el
    __hip_bfloat16* opw_b = ipw_b + 16777216;    // NL*DM*DI  =  8,388,608 el
    __hip_bfloat16* xpw_b = opw_b + 8388608;     // NL*256*2048 = 2,097,152 el
    // split-K partials (aliased onto dead regions):
    float* part_xp = Pc;   // 8 x 2048 x 160 = 2,621,440 fl (Pc+Sc, dead till pass1)
    float* part_h  = xz;   // 4 x 2048 x 1024 = 8,388,608 fl (xz dead after pass2)

    // ---- all weights -> bf16, one kernel
    wconv_all<<<16384 + 8192 + 1024 + 2048, 256, 0, stream>>>(
        in_proj_w, out_proj_w, dt_w, xproj_w, ipw_b, opw_b, dtw_b, xpw_b);

    // ---- fused embedding + layer-0 LN
    embed_ln_k<<<B_ * L_, 256, 0, stream>>>(tokens, tok_emb, pos_emb,
                                            ln_w, ln_b, h, xln_b);

    for (int li = 0; li < NL_; ++li) {
        // xz = x @ in_proj_w^T   (2048 x 4096, K=1024)  [bf16 MFMA]
        gemm_bf16<0><<<dim3(2 * DI_ / 128, B_ * L_ / 128), 256, 0, stream>>>(
            xln_b, DM_, ipw_b + (size_t)li * 2 * DI_ * DM_, DM_,
            xz, 2 * DI_, DM_, 0, nullptr);

        // x_branch = silu(conv(xz[...,:DI]))  -> bf16
        conv_silu<<<B_ * L_ * DI_ / 256, 256, 0, stream>>>(
            xz, conv_w + li * DI_ * K_, conv_b + li * DI_, xb_b);

        // xp = x_branch @ xproj_w^T  (2048 x 160, K=2048) [bf16 MFMA splitK-8]
        gemm_bf16<3><<<dim3(2, B_ * L_ / 128, 8), 256, 0, stream>>>(
            xb_b, DI_, xpw_b + (size_t)li * 256 * 2048, DI_,
            part_xp, XPD_, DI_ / 8, XPD_, nullptr);
        reduce_xp_k<8><<<B_ * L_ * XPD_ / 1024, 256, 0, stream>>>(
            part_xp, xp, xp_b, (size_t)B_ * L_ * XPD_);

        // delta = softplus(dt_r @ dt_w^T + dt_b)  (2048x2048, K=128) [bf16 MFMA]
        gemm_bf16<4><<<dim3(DI_ / 128, B_ * L_ / 128), 256, 0, stream>>>(
            xp_b, XPD_, dtw_b + (size_t)li * DI_ * DTR_, DTR_,
            dlt, DI_, DTR_, 0, dt_b + li * DI_);

        // chunked selective scan
        ssm_pass1<<<B_ * NC_ * (DI_ / 256), 256, 0, stream>>>(
            xb_b, dlt, xp, A_log + li * DI_ * N_, Pc, Sc);
        ssm_scan<<<B_ * N_ * DI_ / 256, 256, 0, stream>>>(Pc, Sc, hst);
        ssm_pass2<<<B_ * NC_ * (DI_ / 256), 256, 0, stream>>>(
            xb_b, dlt, xp, A_log + li * DI_ * N_, D_param + li * DI_, xz, hst, y_b);

        // h += y @ out_proj_w^T  (2048 x 1024, K=2048) [bf16 MFMA splitK-4]
        gemm_bf16<2><<<dim3(DM_ / 128, B_ * L_ / 128, 4), 256, 0, stream>>>(
            y_b, DI_, opw_b + (size_t)li * DM_ * DI_, DI_,
            part_h, DM_, DI_ / 4, 0, nullptr);

        if (li < NL_ - 1) {
            reduce_ln_k<4><<<B_ * L_, 256, 0, stream>>>(
                part_h, h, ln_w + (li + 1) * DM_, ln_b + (li + 1) * DM_,
                xln_b, (size_t)B_ * L_ * DM_);
        } else {
            reduce_k<4, true><<<B_ * L_ * DM_ / 1024, 256, 0, stream>>>(
                part_h, h, (size_t)B_ * L_ * DM_);
        }
    }

    // fused final LN + head
    head_ln_k<<<B_ * P_, 256, 0, stream>>>(h, fnorm_w, fnorm_b, head_w, out);
}

// Round 6
// 878.404 us; speedup vs baseline: 3.4698x; 1.0511x over previous
//
#include <hip/hip_runtime.h>
#include <hip/hip_bf16.h>
#include <cstdint>
#include <cstddef>

#define B_    8
#define L_    256
#define DM_   1024
#define DI_   2048
#define N_    16
#define K_    4
#define NL_   4
#define DTR_  128
#define P_    97
#define XPD_  160   // DTR + 2N
#define CHUNK_ 32
#define NC_   8     // L / CHUNK

typedef __attribute__((ext_vector_type(8))) short short8;
typedef __attribute__((ext_vector_type(4))) float floatx4;

__device__ __forceinline__ void async16(const void* g, void* l)
{
    __builtin_amdgcn_global_load_lds(
        (const __attribute__((address_space(1))) void*)g,
        (__attribute__((address_space(3))) void*)l,
        16, 0, 0);
}

__device__ __forceinline__ void cvt4(const float* s, __hip_bfloat16* d)
{
    float4 v = *(const float4*)s;
    union { __hip_bfloat16 h[4]; ushort4 u; } t;
    t.h[0] = __float2bfloat16(v.x);
    t.h[1] = __float2bfloat16(v.y);
    t.h[2] = __float2bfloat16(v.z);
    t.h[3] = __float2bfloat16(v.w);
    *(ushort4*)d = t.u;
}

__device__ __forceinline__ float bf2f(__hip_bfloat16 h) { return __bfloat162float(h); }

// ---------------------------------------------------------------------------
// Fused: all weight conversions (16 el/thread) + embedding+LN0 (extra blocks).
// blocks: [0,4096) ipw | [4096,6144) opw | [6144,6400) dtw | [6400,6912) xpw
//         | [6912,8960) embed+LN rows
// ---------------------------------------------------------------------------
__global__ __launch_bounds__(256)
void wconv_embed_k(const float* __restrict__ ipw, const float* __restrict__ opw,
                   const float* __restrict__ dtw, const float* __restrict__ xpw,
                   __hip_bfloat16* __restrict__ ipb, __hip_bfloat16* __restrict__ opb,
                   __hip_bfloat16* __restrict__ dtb, __hip_bfloat16* __restrict__ xpb,
                   const int* __restrict__ tokens, const float* __restrict__ te,
                   const float* __restrict__ pe, const float* __restrict__ lw,
                   const float* __restrict__ lb, float* __restrict__ h,
                   __hip_bfloat16* __restrict__ xout)
{
    __shared__ float red[8];
    int blk = blockIdx.x;
    int tid = threadIdx.x;
    if (blk < 6912) {
        if (blk < 4096) {
            size_t base = (size_t)blk * 4096 + tid * 16;
            #pragma unroll
            for (int g = 0; g < 4; ++g) cvt4(ipw + base + g * 4, ipb + base + g * 4);
        } else if (blk < 6144) {
            size_t base = (size_t)(blk - 4096) * 4096 + tid * 16;
            #pragma unroll
            for (int g = 0; g < 4; ++g) cvt4(opw + base + g * 4, opb + base + g * 4);
        } else if (blk < 6400) {
            size_t base = (size_t)(blk - 6144) * 4096 + tid * 16;
            #pragma unroll
            for (int g = 0; g < 4; ++g) cvt4(dtw + base + g * 4, dtb + base + g * 4);
        } else {
            size_t base = (size_t)(blk - 6400) * 4096 + tid * 16;
            #pragma unroll
            for (int g = 0; g < 4; ++g) {
                size_t i = base + g * 4;
                int col   = (int)(i & 2047);
                int row   = (int)((i >> 11) & 255);
                int layer = (int)(i >> 19);
                if (row < XPD_) {
                    cvt4(xpw + ((size_t)layer * XPD_ + row) * 2048 + col, xpb + i);
                } else {
                    union { __hip_bfloat16 h[4]; ushort4 u; } t;
                    t.h[0] = t.h[1] = t.h[2] = t.h[3] = __float2bfloat16(0.f);
                    *(ushort4*)(xpb + i) = t.u;
                }
            }
        }
        return;
    }
    // ---- embedding + layer-0 LN
    int bl = blk - 6912;
    int l  = bl & (L_ - 1);
    int tok = tokens[bl];
    float4 a = *(const float4*)(te + (size_t)tok * DM_ + tid * 4);
    float4 p = *(const float4*)(pe + (size_t)l * DM_ + tid * 4);
    float4 x = make_float4(a.x + p.x, a.y + p.y, a.z + p.z, a.w + p.w);
    size_t base = (size_t)bl * DM_ + tid * 4;
    *(float4*)(h + base) = x;

    float s  = x.x + x.y + x.z + x.w;
    float s2 = x.x * x.x + x.y * x.y + x.z * x.z + x.w * x.w;
    #pragma unroll
    for (int o = 32; o > 0; o >>= 1) {
        s  += __shfl_down(s, o);
        s2 += __shfl_down(s2, o);
    }
    if ((tid & 63) == 0) { red[tid >> 6] = s; red[4 + (tid >> 6)] = s2; }
    __syncthreads();
    float st  = red[0] + red[1] + red[2] + red[3];
    float s2t = red[4] + red[5] + red[6] + red[7];
    float m   = st * (1.f / DM_);
    float var = s2t * (1.f / DM_) - m * m;
    float rs  = rsqrtf(var + 1e-5f);
    float4 wv = *(const float4*)(lw + tid * 4);
    float4 bv = *(const float4*)(lb + tid * 4);
    union { __hip_bfloat16 h[4]; ushort4 u; } t;
    t.h[0] = __float2bfloat16((x.x - m) * rs * wv.x + bv.x);
    t.h[1] = __float2bfloat16((x.y - m) * rs * wv.y + bv.y);
    t.h[2] = __float2bfloat16((x.z - m) * rs * wv.z + bv.z);
    t.h[3] = __float2bfloat16((x.w - m) * rs * wv.w + bv.w);
    *(ushort4*)(xout + base) = t.u;
}

// ---------------------------------------------------------------------------
// bf16 MFMA GEMM, 128x128 tile, BK=32, global_load_lds w16.
// MODE 0: full-K -> bf16 C
// MODE 2: split-K partial -> fp32 Cp[z][M][ldc]
// MODE 3: split-K partial fp32 with epilogue col<Nb guard (B rows pre-padded)
// MODE 5: full-K, bias+softplus -> bf16 C (dt matmul)
// ---------------------------------------------------------------------------
template<int MODE>
__global__ __launch_bounds__(256)
void gemm_bf16(const __hip_bfloat16* __restrict__ A, int lda,
               const __hip_bfloat16* __restrict__ Bw, int ldb,
               void* __restrict__ Cv, int ldc, int Kp, int Nb,
               const float* __restrict__ bias)
{
    __shared__ __hip_bfloat16 As[128 * 32];
    __shared__ __hip_bfloat16 Bs[128 * 32];
    const int tid  = threadIdx.x;
    const int lane = tid & 63;
    const int wid  = tid >> 6;
    const int wm   = wid >> 1, wn = wid & 1;
    const int mbase = blockIdx.y * 128;
    const int nbase = blockIdx.x * 128;
    const int koff  = (MODE == 2 || MODE == 3) ? blockIdx.z * Kp : 0;

    floatx4 acc[4][4] = {};

    const int f0 = tid * 16;
    const int r0 = f0 >> 6, c0 = f0 & 63;
    const int f1 = f0 + 4096;
    const int r1 = f1 >> 6, c1 = f1 & 63;

    const int fr = lane & 15;
    const int kq = (lane >> 4) * 8;

    for (int k0 = koff; k0 < koff + Kp; k0 += 32) {
        const char* Ag = (const char*)(A + (size_t)mbase * lda + k0);
        const char* Bg = (const char*)(Bw + (size_t)nbase * ldb + k0);
        async16(Ag + (size_t)r0 * lda * 2 + c0, (char*)As + f0);
        async16(Ag + (size_t)r1 * lda * 2 + c1, (char*)As + f1);
        async16(Bg + (size_t)r0 * ldb * 2 + c0, (char*)Bs + f0);
        async16(Bg + (size_t)r1 * ldb * 2 + c1, (char*)Bs + f1);
        __syncthreads();

        short8 af[4], bf[4];
        #pragma unroll
        for (int i = 0; i < 4; ++i) {
            int m = wm * 64 + i * 16 + fr;
            af[i] = *(const short8*)(As + m * 32 + kq);
            int n = wn * 64 + i * 16 + fr;
            bf[i] = *(const short8*)(Bs + n * 32 + kq);
        }
        #pragma unroll
        for (int i = 0; i < 4; ++i)
            #pragma unroll
            for (int j = 0; j < 4; ++j)
                acc[i][j] = __builtin_amdgcn_mfma_f32_16x16x32_bf16(
                    af[i], bf[j], acc[i][j], 0, 0, 0);
        __syncthreads();
    }

    const int cq = lane >> 4;
    float* Cf = (float*)Cv;
    __hip_bfloat16* Ch = (__hip_bfloat16*)Cv;
    size_t zoff = (MODE == 2 || MODE == 3)
                ? (size_t)blockIdx.z * (gridDim.y * 128) * ldc : 0;
    #pragma unroll
    for (int i = 0; i < 4; ++i) {
        #pragma unroll
        for (int j = 0; j < 4; ++j) {
            int col = nbase + wn * 64 + j * 16 + fr;
            if (MODE == 3 && col >= Nb) continue;
            float bv = (MODE == 5) ? bias[col] : 0.f;
            #pragma unroll
            for (int r = 0; r < 4; ++r) {
                int row = mbase + wm * 64 + i * 16 + cq * 4 + r;
                float v = acc[i][j][r];
                size_t off = zoff + (size_t)row * ldc + col;
                if (MODE == 2 || MODE == 3) {
                    Cf[off] = v;
                } else if (MODE == 5) {
                    v += bv;
                    v = (v > 20.f) ? v : log1pf(__expf(v));
                    Ch[off] = __float2bfloat16(v);
                } else {
                    Ch[off] = __float2bfloat16(v);
                }
            }
        }
    }
}

// ---------------------------------------------------------------------------
// Split-K reduce for xp: emit fp32 xp AND bf16 xp_b
// ---------------------------------------------------------------------------
template<int PARTS>
__global__ __launch_bounds__(256)
void reduce_xp_k(const float* __restrict__ p, float* __restrict__ dst,
                 __hip_bfloat16* __restrict__ dst_b, size_t stride)
{
    size_t i = ((size_t)blockIdx.x * 256 + threadIdx.x) * 4;
    float4 s = *(const float4*)(p + i);
    #pragma unroll
    for (int z = 1; z < PARTS; ++z) {
        float4 v = *(const float4*)(p + z * stride + i);
        s.x += v.x; s.y += v.y; s.z += v.z; s.w += v.w;
    }
    *(float4*)(dst + i) = s;
    union { __hip_bfloat16 h[4]; ushort4 u; } t;
    t.h[0] = __float2bfloat16(s.x);
    t.h[1] = __float2bfloat16(s.y);
    t.h[2] = __float2bfloat16(s.z);
    t.h[3] = __float2bfloat16(s.w);
    *(ushort4*)(dst_b + i) = t.u;
}

// ---------------------------------------------------------------------------
// Fused: h[row] += sum_z part[z][row]; then LayerNorm(h[row]) -> bf16 out.
// ---------------------------------------------------------------------------
template<int PARTS>
__global__ __launch_bounds__(256)
void reduce_ln_k(const float* __restrict__ p, float* __restrict__ h,
                 const float* __restrict__ w, const float* __restrict__ b,
                 __hip_bfloat16* __restrict__ out, size_t stride)
{
    __shared__ float red[8];
    int tid = threadIdx.x;
    size_t base = (size_t)blockIdx.x * DM_ + tid * 4;
    float4 x = *(const float4*)(h + base);
    #pragma unroll
    for (int z = 0; z < PARTS; ++z) {
        float4 v = *(const float4*)(p + z * stride + base);
        x.x += v.x; x.y += v.y; x.z += v.z; x.w += v.w;
    }
    *(float4*)(h + base) = x;

    float s  = x.x + x.y + x.z + x.w;
    float s2 = x.x * x.x + x.y * x.y + x.z * x.z + x.w * x.w;
    #pragma unroll
    for (int o = 32; o > 0; o >>= 1) {
        s  += __shfl_down(s, o);
        s2 += __shfl_down(s2, o);
    }
    if ((tid & 63) == 0) { red[tid >> 6] = s; red[4 + (tid >> 6)] = s2; }
    __syncthreads();
    float st  = red[0] + red[1] + red[2] + red[3];
    float s2t = red[4] + red[5] + red[6] + red[7];
    float m   = st * (1.f / DM_);
    float var = s2t * (1.f / DM_) - m * m;
    float rs  = rsqrtf(var + 1e-5f);
    float4 wv = *(const float4*)(w + tid * 4);
    float4 bv = *(const float4*)(b + tid * 4);
    union { __hip_bfloat16 h[4]; ushort4 u; } t;
    t.h[0] = __float2bfloat16((x.x - m) * rs * wv.x + bv.x);
    t.h[1] = __float2bfloat16((x.y - m) * rs * wv.y + bv.y);
    t.h[2] = __float2bfloat16((x.z - m) * rs * wv.z + bv.z);
    t.h[3] = __float2bfloat16((x.w - m) * rs * wv.w + bv.w);
    *(ushort4*)(out + base) = t.u;
}

// ---------------------------------------------------------------------------
// Causal depthwise conv (K=4) + SiLU; bf16 in/out, 4 channels/thread
// ---------------------------------------------------------------------------
__global__ __launch_bounds__(256)
void conv_silu(const __hip_bfloat16* __restrict__ xz, const float* __restrict__ cw,
               const float* __restrict__ cb, __hip_bfloat16* __restrict__ xb_b)
{
    int idx = blockIdx.x * 256 + threadIdx.x;    // over B*L*(DI/4)
    int d  = (idx & 511) << 2;
    int bl = idx >> 9;
    int l  = bl & (L_ - 1);
    float4 w[4];
    #pragma unroll
    for (int j = 0; j < 4; ++j) w[j] = *(const float4*)(cw + (d + j) * 4);
    float4 bb = *(const float4*)(cb + d);
    float acc[4] = {bb.x, bb.y, bb.z, bb.w};
    #pragma unroll
    for (int k = 0; k < 4; ++k) {
        int lk = l + k - 3;
        if (lk >= 0) {
            union { ushort4 u; __hip_bfloat16 h[4]; } xu;
            xu.u = *(const ushort4*)(xz + (size_t)(bl - l + lk) * (2 * DI_) + d);
            #pragma unroll
            for (int j = 0; j < 4; ++j)
                acc[j] += ((const float*)&w[j])[k] * bf2f(xu.h[j]);
        }
    }
    union { __hip_bfloat16 h[4]; ushort4 u; } t;
    #pragma unroll
    for (int j = 0; j < 4; ++j) {
        float v = acc[j] / (1.f + __expf(-acc[j]));
        t.h[j] = __float2bfloat16(v);
    }
    *(ushort4*)(xb_b + (size_t)bl * DI_ + d) = t.u;
}

// ---------------------------------------------------------------------------
// SSM pass1: per-chunk local scan from 0 -> decay product Pc, local state Sc
// ---------------------------------------------------------------------------
__global__ __launch_bounds__(256)
void ssm_pass1(const __hip_bfloat16* __restrict__ xb_b,
               const __hip_bfloat16* __restrict__ dlt_b,
               const float* __restrict__ xp, const float* __restrict__ Alog,
               float* __restrict__ Pc, float* __restrict__ Sc)
{
    int blk = blockIdx.x;
    int dgrp = blk & 7, c = (blk >> 3) & 7, b = blk >> 6;
    int d = (dgrp << 8) + threadIdx.x;
    __shared__ float Bsh[CHUNK_][N_];
    for (int i = threadIdx.x; i < CHUNK_ * N_; i += 256) {
        int t = i >> 4, n = i & 15;
        Bsh[t][n] = xp[(size_t)(b * L_ + c * CHUNK_ + t) * XPD_ + DTR_ + n];
    }
    __syncthreads();
    float a[N_], hn[N_], Pn[N_];
    #pragma unroll
    for (int n = 0; n < N_; ++n) {
        a[n] = -__expf(Alog[d * N_ + n]);
        hn[n] = 0.f; Pn[n] = 1.f;
    }
    for (int t = 0; t < CHUNK_; ++t) {
        size_t off = (size_t)(b * L_ + c * CHUNK_ + t) * DI_ + d;
        float dt = bf2f(dlt_b[off]);
        float xv = bf2f(xb_b[off]);
        float dx = dt * xv;
        #pragma unroll
        for (int n = 0; n < N_; ++n) {
            float dA = __expf(dt * a[n]);
            hn[n] = dA * hn[n] + dx * Bsh[t][n];
            Pn[n] *= dA;
        }
    }
    #pragma unroll
    for (int n = 0; n < N_; ++n) {
        size_t o = ((size_t)((b * NC_ + c) * N_ + n)) * DI_ + d;
        Pc[o] = Pn[n]; Sc[o] = hn[n];
    }
}

// ---------------------------------------------------------------------------
// SSM pass2: prefix over earlier chunks (from Pc/Sc, L2-hot) -> hstart;
// re-run chunk; y = (C.h + x*D) * silu(z) -> bf16
// ---------------------------------------------------------------------------
__global__ __launch_bounds__(256)
void ssm_pass2(const __hip_bfloat16* __restrict__ xb_b,
               const __hip_bfloat16* __restrict__ dlt_b,
               const float* __restrict__ xp, const float* __restrict__ Alog,
               const float* __restrict__ Dp, const __hip_bfloat16* __restrict__ xz,
               const float* __restrict__ Pc, const float* __restrict__ Sc,
               __hip_bfloat16* __restrict__ yout)
{
    int blk = blockIdx.x;
    int dgrp = blk & 7, c = (blk >> 3) & 7, b = blk >> 6;
    int d = (dgrp << 8) + threadIdx.x;
    __shared__ float Bsh[CHUNK_][N_], Csh[CHUNK_][N_];
    for (int i = threadIdx.x; i < CHUNK_ * 2 * N_; i += 256) {
        int t = i >> 5, j = i & 31;
        float v = xp[(size_t)(b * L_ + c * CHUNK_ + t) * XPD_ + DTR_ + j];
        if (j < 16) Bsh[t][j] = v; else Csh[t][j - 16] = v;
    }
    __syncthreads();
    float a[N_], hn[N_];
    #pragma unroll
    for (int n = 0; n < N_; ++n) {
        a[n] = -__expf(Alog[d * N_ + n]);
        hn[n] = 0.f;
    }
    // prefix over earlier chunks
    for (int cp = 0; cp < c; ++cp) {
        #pragma unroll
        for (int n = 0; n < N_; ++n) {
            size_t o = ((size_t)((b * NC_ + cp) * N_ + n)) * DI_ + d;
            hn[n] = Pc[o] * hn[n] + Sc[o];
        }
    }
    float dpv = Dp[d];
    for (int t = 0; t < CHUNK_; ++t) {
        int l = c * CHUNK_ + t;
        size_t off = (size_t)(b * L_ + l) * DI_ + d;
        float dt = bf2f(dlt_b[off]);
        float xv = bf2f(xb_b[off]);
        float dx = dt * xv;
        float yv = 0.f;
        #pragma unroll
        for (int n = 0; n < N_; ++n) {
            float dA = __expf(dt * a[n]);
            hn[n] = dA * hn[n] + dx * Bsh[t][n];
            yv += hn[n] * Csh[t][n];
        }
        yv += xv * dpv;
        float z = bf2f(xz[(size_t)(b * L_ + l) * (2 * DI_) + DI_ + d]);
        yout[off] = __float2bfloat16(yv * z / (1.f + __expf(-z)));
    }
}

// ---------------------------------------------------------------------------
// Fused last-layer part-sum + final LayerNorm + head.
// x = h[row] + part[0][row] + part[1][row]; out = rs*(t1 - m*t2) + t3.
// ---------------------------------------------------------------------------
__global__ __launch_bounds__(256)
void head_ln_k(const float* __restrict__ h, const float* __restrict__ parts,
               size_t pstride,
               const float* __restrict__ fw, const float* __restrict__ fb,
               const float* __restrict__ hw, float* __restrict__ out)
{
    __shared__ float red[4][5];
    int b = blockIdx.x / P_;
    int p = blockIdx.x % P_;
    int tid = threadIdx.x;
    size_t rowoff = ((size_t)(b * L_ + L_ - 1)) * DM_ + tid * 4;
    float4 x  = *(const float4*)(h + rowoff);
    float4 p0 = *(const float4*)(parts + rowoff);
    float4 p1 = *(const float4*)(parts + pstride + rowoff);
    x.x += p0.x + p1.x; x.y += p0.y + p1.y;
    x.z += p0.z + p1.z; x.w += p0.w + p1.w;
    float4 w4 = *(const float4*)(fw + tid * 4);
    float4 b4 = *(const float4*)(fb + tid * 4);
    float4 g4 = *(const float4*)(hw + (size_t)p * DM_ + tid * 4);
    float s  = x.x + x.y + x.z + x.w;
    float s2 = x.x * x.x + x.y * x.y + x.z * x.z + x.w * x.w;
    float t1 = x.x * w4.x * g4.x + x.y * w4.y * g4.y + x.z * w4.z * g4.z + x.w * w4.w * g4.w;
    float t2 = w4.x * g4.x + w4.y * g4.y + w4.z * g4.z + w4.w * g4.w;
    float t3 = b4.x * g4.x + b4.y * g4.y + b4.z * g4.z + b4.w * g4.w;
    #pragma unroll
    for (int o = 32; o > 0; o >>= 1) {
        s  += __shfl_down(s, o);
        s2 += __shfl_down(s2, o);
        t1 += __shfl_down(t1, o);
        t2 += __shfl_down(t2, o);
        t3 += __shfl_down(t3, o);
    }
    if ((tid & 63) == 0) {
        int w = tid >> 6;
        red[w][0] = s; red[w][1] = s2; red[w][2] = t1; red[w][3] = t2; red[w][4] = t3;
    }
    __syncthreads();
    if (tid == 0) {
        float st  = red[0][0] + red[1][0] + red[2][0] + red[3][0];
        float s2t = red[0][1] + red[1][1] + red[2][1] + red[3][1];
        float t1t = red[0][2] + red[1][2] + red[2][2] + red[3][2];
        float t2t = red[0][3] + red[1][3] + red[2][3] + red[3][3];
        float t3t = red[0][4] + red[1][4] + red[2][4] + red[3][4];
        float m   = st * (1.f / DM_);
        float var = s2t * (1.f / DM_) - m * m;
        float rs  = rsqrtf(var + 1e-5f);
        out[blockIdx.x] = rs * (t1t - m * t2t) + t3t;
    }
}

// ---------------------------------------------------------------------------
extern "C" void kernel_launch(void* const* d_in, const int* in_sizes, int n_in,
                              void* d_out, int out_size, void* d_ws, size_t ws_size,
                              hipStream_t stream)
{
    const int*   tokens     = (const int*)  d_in[0];
    const float* tok_emb    = (const float*)d_in[1];
    const float* pos_emb    = (const float*)d_in[2];
    const float* ln_w       = (const float*)d_in[3];
    const float* ln_b       = (const float*)d_in[4];
    const float* in_proj_w  = (const float*)d_in[5];
    const float* conv_w     = (const float*)d_in[6];
    const float* conv_b     = (const float*)d_in[7];
    const float* xproj_w    = (const float*)d_in[8];
    const float* dt_w       = (const float*)d_in[9];
    const float* dt_b       = (const float*)d_in[10];
    const float* A_log      = (const float*)d_in[11];
    const float* D_param    = (const float*)d_in[12];
    const float* out_proj_w = (const float*)d_in[13];
    const float* fnorm_w    = (const float*)d_in[14];
    const float* fnorm_b    = (const float*)d_in[15];
    const float* head_w     = (const float*)d_in[16];
    float* out = (float*)d_out;
    float* ws  = (float*)d_ws;

    // fp32 workspace (floats)
    float* h      = ws;                   // B*L*DM    = 2,097,152
    float* xp     = h    + 2097152;       // B*L*XPD   =   327,680
    float* Pc     = xp   + 327680;        // B*NC*N*DI = 2,097,152
    float* Sc     = Pc   + 2097152;       // 2,097,152
    float* part_h = Sc   + 2097152;       // 2 x B*L*DM = 4,194,304
    // bf16 workspace
    __hip_bfloat16* bfb = (__hip_bfloat16*)(part_h + 4194304);
    __hip_bfloat16* xz_b  = bfb;                 // B*L*2DI = 8,388,608 el
    __hip_bfloat16* xln_b = xz_b  + 8388608;     // B*L*DM  = 2,097,152 el
    __hip_bfloat16* y_b   = xln_b + 2097152;     // B*L*DI  = 4,194,304 el
    __hip_bfloat16* xb_b  = y_b   + 4194304;     // B*L*DI  = 4,194,304 el
    __hip_bfloat16* dlt_b = xb_b  + 4194304;     // B*L*DI  = 4,194,304 el
    __hip_bfloat16* xp_b  = dlt_b + 4194304;     // B*L*XPD =   327,680 el
    __hip_bfloat16* dtw_b = xp_b  + 327680;      // NL*DI*DTR = 1,048,576 el
    __hip_bfloat16* ipw_b = dtw_b + 1048576;     // NL*2DI*DM = 16,777,216 el
    __hip_bfloat16* opw_b = ipw_b + 16777216;    // NL*DM*DI  =  8,388,608 el
    __hip_bfloat16* xpw_b = opw_b + 8388608;     // NL*256*2048 = 2,097,152 el
    // split-K partials for xproj alias Pc+Sc (dead until ssm_pass1)
    float* part_xp = Pc;   // 8 x 2048 x 160 = 2,621,440 fl <= 4,194,304 fl

    // ---- weights -> bf16 + embedding + layer-0 LN, one launch
    wconv_embed_k<<<6912 + B_ * L_, 256, 0, stream>>>(
        in_proj_w, out_proj_w, dt_w, xproj_w, ipw_b, opw_b, dtw_b, xpw_b,
        tokens, tok_emb, pos_emb, ln_w, ln_b, h, xln_b);

    for (int li = 0; li < NL_; ++li) {
        // xz = x @ in_proj_w^T  (2048 x 4096, K=1024) -> bf16
        gemm_bf16<0><<<dim3(2 * DI_ / 128, B_ * L_ / 128), 256, 0, stream>>>(
            xln_b, DM_, ipw_b + (size_t)li * 2 * DI_ * DM_, DM_,
            xz_b, 2 * DI_, DM_, 0, nullptr);

        // x_branch = silu(conv(xz[...,:DI]))  -> bf16 (4 ch/thread)
        conv_silu<<<B_ * L_ * DI_ / 4 / 256, 256, 0, stream>>>(
            xz_b, conv_w + li * DI_ * K_, conv_b + li * DI_, xb_b);

        // xp = x_branch @ xproj_w^T  (2048 x 160, K=2048) [splitK-8]
        gemm_bf16<3><<<dim3(2, B_ * L_ / 128, 8), 256, 0, stream>>>(
            xb_b, DI_, xpw_b + (size_t)li * 256 * 2048, DI_,
            part_xp, XPD_, DI_ / 8, XPD_, nullptr);
        reduce_xp_k<8><<<B_ * L_ * XPD_ / 1024, 256, 0, stream>>>(
            part_xp, xp, xp_b, (size_t)B_ * L_ * XPD_);

        // delta = softplus(dt_r @ dt_w^T + dt_b)  (2048x2048, K=128) -> bf16
        gemm_bf16<5><<<dim3(DI_ / 128, B_ * L_ / 128), 256, 0, stream>>>(
            xp_b, XPD_, dtw_b + (size_t)li * DI_ * DTR_, DTR_,
            dlt_b, DI_, DTR_, 0, dt_b + li * DI_);

        // chunked selective scan (scan prefix folded into pass2)
        ssm_pass1<<<B_ * NC_ * (DI_ / 256), 256, 0, stream>>>(
            xb_b, dlt_b, xp, A_log + li * DI_ * N_, Pc, Sc);
        ssm_pass2<<<B_ * NC_ * (DI_ / 256), 256, 0, stream>>>(
            xb_b, dlt_b, xp, A_log + li * DI_ * N_, D_param + li * DI_,
            xz_b, Pc, Sc, y_b);

        // h += y @ out_proj_w^T  (2048 x 1024, K=2048) [splitK-2]
        gemm_bf16<2><<<dim3(DM_ / 128, B_ * L_ / 128, 2), 256, 0, stream>>>(
            y_b, DI_, opw_b + (size_t)li * DM_ * DI_, DI_,
            part_h, DM_, DI_ / 2, 0, nullptr);

        if (li < NL_ - 1) {
            reduce_ln_k<2><<<B_ * L_, 256, 0, stream>>>(
                part_h, h, ln_w + (li + 1) * DM_, ln_b + (li + 1) * DM_,
                xln_b, (size_t)B_ * L_ * DM_);
        }
        // last layer: part-sum folded into head_ln_k
    }

    // fused last-layer residual + final LN + head
    head_ln_k<<<B_ * P_, 256, 0, stream>>>(
        h, part_h, (size_t)B_ * L_ * DM_, fnorm_w, fnorm_b, head_w, out);
}

// Round 7
// 832.026 us; speedup vs baseline: 3.6632x; 1.0557x over previous
//
#include <hip/hip_runtime.h>
#include <hip/hip_bf16.h>
#include <cstdint>
#include <cstddef>

#define B_    8
#define L_    256
#define DM_   1024
#define DI_   2048
#define N_    16
#define K_    4
#define NL_   4
#define DTR_  128
#define P_    97
#define XPD_  160   // DTR + 2N
#define CHUNK_ 32
#define NC_   8     // L / CHUNK

typedef __attribute__((ext_vector_type(8))) short short8;
typedef __attribute__((ext_vector_type(4))) float floatx4;

__device__ __forceinline__ void async16(const void* g, void* l)
{
    __builtin_amdgcn_global_load_lds(
        (const __attribute__((address_space(1))) void*)g,
        (__attribute__((address_space(3))) void*)l,
        16, 0, 0);
}

__device__ __forceinline__ float bf2f(__hip_bfloat16 h) { return __bfloat162float(h); }

__device__ __forceinline__ void cvt8(const float* s, __hip_bfloat16* d)
{
    float4 a = *(const float4*)s;
    float4 b = *(const float4*)(s + 4);
    union { __hip_bfloat16 h[8]; short8 u; } t;
    t.h[0] = __float2bfloat16(a.x); t.h[1] = __float2bfloat16(a.y);
    t.h[2] = __float2bfloat16(a.z); t.h[3] = __float2bfloat16(a.w);
    t.h[4] = __float2bfloat16(b.x); t.h[5] = __float2bfloat16(b.y);
    t.h[6] = __float2bfloat16(b.z); t.h[7] = __float2bfloat16(b.w);
    *(short8*)d = t.u;
}

// ---------------------------------------------------------------------------
// Fused: all weight conversions (8 el/thread, 16B stores) + embed+LN0.
// blocks: [0,8192) ipw | [8192,12288) opw | [12288,12800) dtw |
//         [12800,13824) xpw | [13824,15872) embed+LN rows
// ---------------------------------------------------------------------------
__global__ __launch_bounds__(256)
void wconv_embed_k(const float* __restrict__ ipw, const float* __restrict__ opw,
                   const float* __restrict__ dtw, const float* __restrict__ xpw,
                   __hip_bfloat16* __restrict__ ipb, __hip_bfloat16* __restrict__ opb,
                   __hip_bfloat16* __restrict__ dtb, __hip_bfloat16* __restrict__ xpb,
                   const int* __restrict__ tokens, const float* __restrict__ te,
                   const float* __restrict__ pe, const float* __restrict__ lw,
                   const float* __restrict__ lb, float* __restrict__ h,
                   __hip_bfloat16* __restrict__ xout)
{
    __shared__ float red[8];
    int blk = blockIdx.x;
    int tid = threadIdx.x;
    if (blk < 13824) {
        if (blk < 8192) {
            size_t i = (size_t)blk * 2048 + tid * 8;
            cvt8(ipw + i, ipb + i);
        } else if (blk < 12288) {
            size_t i = (size_t)(blk - 8192) * 2048 + tid * 8;
            cvt8(opw + i, opb + i);
        } else if (blk < 12800) {
            size_t i = (size_t)(blk - 12288) * 2048 + tid * 8;
            cvt8(dtw + i, dtb + i);
        } else {
            size_t i = (size_t)(blk - 12800) * 2048 + tid * 8;  // NL*256*2048
            int col   = (int)(i & 2047);
            int row   = (int)((i >> 11) & 255);
            int layer = (int)(i >> 19);
            if (row < XPD_) {
                cvt8(xpw + ((size_t)layer * XPD_ + row) * 2048 + col, xpb + i);
            } else {
                union { __hip_bfloat16 h[8]; short8 u; } t;
                #pragma unroll
                for (int j = 0; j < 8; ++j) t.h[j] = __float2bfloat16(0.f);
                *(short8*)(xpb + i) = t.u;
            }
        }
        return;
    }
    // ---- embedding + layer-0 LN
    int bl = blk - 13824;
    int l  = bl & (L_ - 1);
    int tok = tokens[bl];
    float4 a = *(const float4*)(te + (size_t)tok * DM_ + tid * 4);
    float4 p = *(const float4*)(pe + (size_t)l * DM_ + tid * 4);
    float4 x = make_float4(a.x + p.x, a.y + p.y, a.z + p.z, a.w + p.w);
    size_t base = (size_t)bl * DM_ + tid * 4;
    *(float4*)(h + base) = x;

    float s  = x.x + x.y + x.z + x.w;
    float s2 = x.x * x.x + x.y * x.y + x.z * x.z + x.w * x.w;
    #pragma unroll
    for (int o = 32; o > 0; o >>= 1) {
        s  += __shfl_down(s, o);
        s2 += __shfl_down(s2, o);
    }
    if ((tid & 63) == 0) { red[tid >> 6] = s; red[4 + (tid >> 6)] = s2; }
    __syncthreads();
    float st  = red[0] + red[1] + red[2] + red[3];
    float s2t = red[4] + red[5] + red[6] + red[7];
    float m   = st * (1.f / DM_);
    float var = s2t * (1.f / DM_) - m * m;
    float rs  = rsqrtf(var + 1e-5f);
    float4 wv = *(const float4*)(lw + tid * 4);
    float4 bv = *(const float4*)(lb + tid * 4);
    union { __hip_bfloat16 h[4]; ushort4 u; } t;
    t.h[0] = __float2bfloat16((x.x - m) * rs * wv.x + bv.x);
    t.h[1] = __float2bfloat16((x.y - m) * rs * wv.y + bv.y);
    t.h[2] = __float2bfloat16((x.z - m) * rs * wv.z + bv.z);
    t.h[3] = __float2bfloat16((x.w - m) * rs * wv.w + bv.w);
    *(ushort4*)(xout + base) = t.u;
}

// ---------------------------------------------------------------------------
// bf16 MFMA GEMM, 128xTN tile (TN = 128 or 64), BK=32, global_load_lds w16.
// MODE 0: full-K -> bf16 C
// MODE 2: split-K partial -> fp32 Cp[z][M][ldc]
// MODE 3: split-K partial fp32 with epilogue col<Nb guard (B rows pre-padded)
// MODE 5: full-K, bias+softplus -> bf16 C (dt matmul)
// Waves 2x2: wave = rows wm*64..+64, cols wn*(TN/2)..+(TN/2).
// ---------------------------------------------------------------------------
template<int MODE, int TN>
__global__ __launch_bounds__(256)
void gemm_bf16(const __hip_bfloat16* __restrict__ A, int lda,
               const __hip_bfloat16* __restrict__ Bw, int ldb,
               void* __restrict__ Cv, int ldc, int Kp, int Nb,
               const float* __restrict__ bias)
{
    constexpr int JW = (TN == 128) ? 4 : 2;
    __shared__ __hip_bfloat16 As[128 * 32];
    __shared__ __hip_bfloat16 Bs[TN * 32];
    const int tid  = threadIdx.x;
    const int lane = tid & 63;
    const int wid  = tid >> 6;
    const int wm   = wid >> 1, wn = wid & 1;
    const int mbase = blockIdx.y * 128;
    const int nbase = blockIdx.x * TN;
    const int koff  = (MODE == 2 || MODE == 3) ? blockIdx.z * Kp : 0;

    floatx4 acc[4][JW] = {};

    const int f0 = tid * 16;
    const int r0 = f0 >> 6, c0 = f0 & 63;
    const int f1 = f0 + 4096;
    const int r1 = f1 >> 6, c1 = f1 & 63;

    const int fr = lane & 15;
    const int kq = (lane >> 4) * 8;

    for (int k0 = koff; k0 < koff + Kp; k0 += 32) {
        const char* Ag = (const char*)(A + (size_t)mbase * lda + k0);
        const char* Bg = (const char*)(Bw + (size_t)nbase * ldb + k0);
        async16(Ag + (size_t)r0 * lda * 2 + c0, (char*)As + f0);
        async16(Ag + (size_t)r1 * lda * 2 + c1, (char*)As + f1);
        async16(Bg + (size_t)r0 * ldb * 2 + c0, (char*)Bs + f0);
        if constexpr (TN == 128)
            async16(Bg + (size_t)r1 * ldb * 2 + c1, (char*)Bs + f1);
        __syncthreads();

        short8 af[4], bf[JW];
        #pragma unroll
        for (int i = 0; i < 4; ++i) {
            int m = wm * 64 + i * 16 + fr;
            af[i] = *(const short8*)(As + m * 32 + kq);
        }
        #pragma unroll
        for (int j = 0; j < JW; ++j) {
            int n = wn * (TN / 2) + j * 16 + fr;
            bf[j] = *(const short8*)(Bs + n * 32 + kq);
        }
        #pragma unroll
        for (int i = 0; i < 4; ++i)
            #pragma unroll
            for (int j = 0; j < JW; ++j)
                acc[i][j] = __builtin_amdgcn_mfma_f32_16x16x32_bf16(
                    af[i], bf[j], acc[i][j], 0, 0, 0);
        __syncthreads();
    }

    const int cq = lane >> 4;
    float* Cf = (float*)Cv;
    __hip_bfloat16* Ch = (__hip_bfloat16*)Cv;
    size_t zoff = (MODE == 2 || MODE == 3)
                ? (size_t)blockIdx.z * (gridDim.y * 128) * ldc : 0;
    #pragma unroll
    for (int i = 0; i < 4; ++i) {
        #pragma unroll
        for (int j = 0; j < JW; ++j) {
            int col = nbase + wn * (TN / 2) + j * 16 + fr;
            if (MODE == 3 && col >= Nb) continue;
            float bv = (MODE == 5) ? bias[col] : 0.f;
            #pragma unroll
            for (int r = 0; r < 4; ++r) {
                int row = mbase + wm * 64 + i * 16 + cq * 4 + r;
                float v = acc[i][j][r];
                size_t off = zoff + (size_t)row * ldc + col;
                if (MODE == 2 || MODE == 3) {
                    Cf[off] = v;
                } else if (MODE == 5) {
                    v += bv;
                    v = (v > 20.f) ? v : log1pf(__expf(v));
                    Ch[off] = __float2bfloat16(v);
                } else {
                    Ch[off] = __float2bfloat16(v);
                }
            }
        }
    }
}

// ---------------------------------------------------------------------------
// Split-K reduce for xp: emit fp32 xp AND bf16 xp_b
// ---------------------------------------------------------------------------
template<int PARTS>
__global__ __launch_bounds__(256)
void reduce_xp_k(const float* __restrict__ p, float* __restrict__ dst,
                 __hip_bfloat16* __restrict__ dst_b, size_t stride)
{
    size_t i = ((size_t)blockIdx.x * 256 + threadIdx.x) * 4;
    float4 s = *(const float4*)(p + i);
    #pragma unroll
    for (int z = 1; z < PARTS; ++z) {
        float4 v = *(const float4*)(p + z * stride + i);
        s.x += v.x; s.y += v.y; s.z += v.z; s.w += v.w;
    }
    *(float4*)(dst + i) = s;
    union { __hip_bfloat16 h[4]; ushort4 u; } t;
    t.h[0] = __float2bfloat16(s.x);
    t.h[1] = __float2bfloat16(s.y);
    t.h[2] = __float2bfloat16(s.z);
    t.h[3] = __float2bfloat16(s.w);
    *(ushort4*)(dst_b + i) = t.u;
}

// ---------------------------------------------------------------------------
// Fused: h[row] += sum_z part[z][row]; then LayerNorm(h[row]) -> bf16 out.
// ---------------------------------------------------------------------------
template<int PARTS>
__global__ __launch_bounds__(256)
void reduce_ln_k(const float* __restrict__ p, float* __restrict__ h,
                 const float* __restrict__ w, const float* __restrict__ b,
                 __hip_bfloat16* __restrict__ out, size_t stride)
{
    __shared__ float red[8];
    int tid = threadIdx.x;
    size_t base = (size_t)blockIdx.x * DM_ + tid * 4;
    float4 x = *(const float4*)(h + base);
    #pragma unroll
    for (int z = 0; z < PARTS; ++z) {
        float4 v = *(const float4*)(p + z * stride + base);
        x.x += v.x; x.y += v.y; x.z += v.z; x.w += v.w;
    }
    *(float4*)(h + base) = x;

    float s  = x.x + x.y + x.z + x.w;
    float s2 = x.x * x.x + x.y * x.y + x.z * x.z + x.w * x.w;
    #pragma unroll
    for (int o = 32; o > 0; o >>= 1) {
        s  += __shfl_down(s, o);
        s2 += __shfl_down(s2, o);
    }
    if ((tid & 63) == 0) { red[tid >> 6] = s; red[4 + (tid >> 6)] = s2; }
    __syncthreads();
    float st  = red[0] + red[1] + red[2] + red[3];
    float s2t = red[4] + red[5] + red[6] + red[7];
    float m   = st * (1.f / DM_);
    float var = s2t * (1.f / DM_) - m * m;
    float rs  = rsqrtf(var + 1e-5f);
    float4 wv = *(const float4*)(w + tid * 4);
    float4 bv = *(const float4*)(b + tid * 4);
    union { __hip_bfloat16 h[4]; ushort4 u; } t;
    t.h[0] = __float2bfloat16((x.x - m) * rs * wv.x + bv.x);
    t.h[1] = __float2bfloat16((x.y - m) * rs * wv.y + bv.y);
    t.h[2] = __float2bfloat16((x.z - m) * rs * wv.z + bv.z);
    t.h[3] = __float2bfloat16((x.w - m) * rs * wv.w + bv.w);
    *(ushort4*)(out + base) = t.u;
}

// ---------------------------------------------------------------------------
// Causal depthwise conv (K=4) + SiLU; bf16 in/out, 8 channels/thread (16B)
// ---------------------------------------------------------------------------
__global__ __launch_bounds__(256)
void conv_silu(const __hip_bfloat16* __restrict__ xz, const float* __restrict__ cw,
               const float* __restrict__ cb, __hip_bfloat16* __restrict__ xb_b)
{
    int idx = blockIdx.x * 256 + threadIdx.x;    // over B*L*(DI/8)
    int d  = (idx & 255) << 3;
    int bl = idx >> 8;
    int l  = bl & (L_ - 1);
    float4 w[8];
    #pragma unroll
    for (int j = 0; j < 8; ++j) w[j] = *(const float4*)(cw + (d + j) * 4);
    float acc[8];
    {
        float4 b0 = *(const float4*)(cb + d);
        float4 b1 = *(const float4*)(cb + d + 4);
        acc[0] = b0.x; acc[1] = b0.y; acc[2] = b0.z; acc[3] = b0.w;
        acc[4] = b1.x; acc[5] = b1.y; acc[6] = b1.z; acc[7] = b1.w;
    }
    #pragma unroll
    for (int k = 0; k < 4; ++k) {
        int lk = l + k - 3;
        if (lk >= 0) {
            union { short8 u; __hip_bfloat16 h[8]; } xu;
            xu.u = *(const short8*)(xz + (size_t)(bl - l + lk) * (2 * DI_) + d);
            #pragma unroll
            for (int j = 0; j < 8; ++j)
                acc[j] += ((const float*)&w[j])[k] * bf2f(xu.h[j]);
        }
    }
    union { __hip_bfloat16 h[8]; short8 u; } t;
    #pragma unroll
    for (int j = 0; j < 8; ++j) {
        float v = acc[j] / (1.f + __expf(-acc[j]));
        t.h[j] = __float2bfloat16(v);
    }
    *(short8*)(xb_b + (size_t)bl * DI_ + d) = t.u;
}

// ---------------------------------------------------------------------------
// SSM pass1: per-chunk local scan from 0 -> decay product Pc, local state Sc
// ---------------------------------------------------------------------------
__global__ __launch_bounds__(256)
void ssm_pass1(const __hip_bfloat16* __restrict__ xb_b,
               const __hip_bfloat16* __restrict__ dlt_b,
               const float* __restrict__ xp, const float* __restrict__ Alog,
               float* __restrict__ Pc, float* __restrict__ Sc)
{
    int blk = blockIdx.x;
    int dgrp = blk & 7, c = (blk >> 3) & 7, b = blk >> 6;
    int d = (dgrp << 8) + threadIdx.x;
    __shared__ float Bsh[CHUNK_][N_];
    for (int i = threadIdx.x; i < CHUNK_ * N_; i += 256) {
        int t = i >> 4, n = i & 15;
        Bsh[t][n] = xp[(size_t)(b * L_ + c * CHUNK_ + t) * XPD_ + DTR_ + n];
    }
    __syncthreads();
    float a[N_], hn[N_], Pn[N_];
    #pragma unroll
    for (int n = 0; n < N_; ++n) {
        a[n] = -__expf(Alog[d * N_ + n]);
        hn[n] = 0.f; Pn[n] = 1.f;
    }
    for (int t = 0; t < CHUNK_; ++t) {
        size_t off = (size_t)(b * L_ + c * CHUNK_ + t) * DI_ + d;
        float dt = bf2f(dlt_b[off]);
        float xv = bf2f(xb_b[off]);
        float dx = dt * xv;
        #pragma unroll
        for (int n = 0; n < N_; ++n) {
            float dA = __expf(dt * a[n]);
            hn[n] = dA * hn[n] + dx * Bsh[t][n];
            Pn[n] *= dA;
        }
    }
    #pragma unroll
    for (int n = 0; n < N_; ++n) {
        size_t o = ((size_t)((b * NC_ + c) * N_ + n)) * DI_ + d;
        Pc[o] = Pn[n]; Sc[o] = hn[n];
    }
}

// ---------------------------------------------------------------------------
// SSM pass2: prefix over earlier chunks (Pc/Sc L2-hot); re-run chunk;
// y = (C.h + x*D) * silu(z) -> bf16
// ---------------------------------------------------------------------------
__global__ __launch_bounds__(256)
void ssm_pass2(const __hip_bfloat16* __restrict__ xb_b,
               const __hip_bfloat16* __restrict__ dlt_b,
               const float* __restrict__ xp, const float* __restrict__ Alog,
               const float* __restrict__ Dp, const __hip_bfloat16* __restrict__ xz,
               const float* __restrict__ Pc, const float* __restrict__ Sc,
               __hip_bfloat16* __restrict__ yout)
{
    int blk = blockIdx.x;
    int dgrp = blk & 7, c = (blk >> 3) & 7, b = blk >> 6;
    int d = (dgrp << 8) + threadIdx.x;
    __shared__ float Bsh[CHUNK_][N_], Csh[CHUNK_][N_];
    for (int i = threadIdx.x; i < CHUNK_ * 2 * N_; i += 256) {
        int t = i >> 5, j = i & 31;
        float v = xp[(size_t)(b * L_ + c * CHUNK_ + t) * XPD_ + DTR_ + j];
        if (j < 16) Bsh[t][j] = v; else Csh[t][j - 16] = v;
    }
    __syncthreads();
    float a[N_], hn[N_];
    #pragma unroll
    for (int n = 0; n < N_; ++n) {
        a[n] = -__expf(Alog[d * N_ + n]);
        hn[n] = 0.f;
    }
    for (int cp = 0; cp < c; ++cp) {
        #pragma unroll
        for (int n = 0; n < N_; ++n) {
            size_t o = ((size_t)((b * NC_ + cp) * N_ + n)) * DI_ + d;
            hn[n] = Pc[o] * hn[n] + Sc[o];
        }
    }
    float dpv = Dp[d];
    for (int t = 0; t < CHUNK_; ++t) {
        int l = c * CHUNK_ + t;
        size_t off = (size_t)(b * L_ + l) * DI_ + d;
        float dt = bf2f(dlt_b[off]);
        float xv = bf2f(xb_b[off]);
        float dx = dt * xv;
        float yv = 0.f;
        #pragma unroll
        for (int n = 0; n < N_; ++n) {
            float dA = __expf(dt * a[n]);
            hn[n] = dA * hn[n] + dx * Bsh[t][n];
            yv += hn[n] * Csh[t][n];
        }
        yv += xv * dpv;
        float z = bf2f(xz[(size_t)(b * L_ + l) * (2 * DI_) + DI_ + d]);
        yout[off] = __float2bfloat16(yv * z / (1.f + __expf(-z)));
    }
}

// ---------------------------------------------------------------------------
// Fused last-layer part-sum + final LayerNorm + head.
// ---------------------------------------------------------------------------
__global__ __launch_bounds__(256)
void head_ln_k(const float* __restrict__ h, const float* __restrict__ parts,
               size_t pstride,
               const float* __restrict__ fw, const float* __restrict__ fb,
               const float* __restrict__ hw, float* __restrict__ out)
{
    __shared__ float red[4][5];
    int b = blockIdx.x / P_;
    int p = blockIdx.x % P_;
    int tid = threadIdx.x;
    size_t rowoff = ((size_t)(b * L_ + L_ - 1)) * DM_ + tid * 4;
    float4 x  = *(const float4*)(h + rowoff);
    float4 p0 = *(const float4*)(parts + rowoff);
    float4 p1 = *(const float4*)(parts + pstride + rowoff);
    x.x += p0.x + p1.x; x.y += p0.y + p1.y;
    x.z += p0.z + p1.z; x.w += p0.w + p1.w;
    float4 w4 = *(const float4*)(fw + tid * 4);
    float4 b4 = *(const float4*)(fb + tid * 4);
    float4 g4 = *(const float4*)(hw + (size_t)p * DM_ + tid * 4);
    float s  = x.x + x.y + x.z + x.w;
    float s2 = x.x * x.x + x.y * x.y + x.z * x.z + x.w * x.w;
    float t1 = x.x * w4.x * g4.x + x.y * w4.y * g4.y + x.z * w4.z * g4.z + x.w * w4.w * g4.w;
    float t2 = w4.x * g4.x + w4.y * g4.y + w4.z * g4.z + w4.w * g4.w;
    float t3 = b4.x * g4.x + b4.y * g4.y + b4.z * g4.z + b4.w * g4.w;
    #pragma unroll
    for (int o = 32; o > 0; o >>= 1) {
        s  += __shfl_down(s, o);
        s2 += __shfl_down(s2, o);
        t1 += __shfl_down(t1, o);
        t2 += __shfl_down(t2, o);
        t3 += __shfl_down(t3, o);
    }
    if ((tid & 63) == 0) {
        int w = tid >> 6;
        red[w][0] = s; red[w][1] = s2; red[w][2] = t1; red[w][3] = t2; red[w][4] = t3;
    }
    __syncthreads();
    if (tid == 0) {
        float st  = red[0][0] + red[1][0] + red[2][0] + red[3][0];
        float s2t = red[0][1] + red[1][1] + red[2][1] + red[3][1];
        float t1t = red[0][2] + red[1][2] + red[2][2] + red[3][2];
        float t2t = red[0][3] + red[1][3] + red[2][3] + red[3][3];
        float t3t = red[0][4] + red[1][4] + red[2][4] + red[3][4];
        float m   = st * (1.f / DM_);
        float var = s2t * (1.f / DM_) - m * m;
        float rs  = rsqrtf(var + 1e-5f);
        out[blockIdx.x] = rs * (t1t - m * t2t) + t3t;
    }
}

// ---------------------------------------------------------------------------
extern "C" void kernel_launch(void* const* d_in, const int* in_sizes, int n_in,
                              void* d_out, int out_size, void* d_ws, size_t ws_size,
                              hipStream_t stream)
{
    const int*   tokens     = (const int*)  d_in[0];
    const float* tok_emb    = (const float*)d_in[1];
    const float* pos_emb    = (const float*)d_in[2];
    const float* ln_w       = (const float*)d_in[3];
    const float* ln_b       = (const float*)d_in[4];
    const float* in_proj_w  = (const float*)d_in[5];
    const float* conv_w     = (const float*)d_in[6];
    const float* conv_b     = (const float*)d_in[7];
    const float* xproj_w    = (const float*)d_in[8];
    const float* dt_w       = (const float*)d_in[9];
    const float* dt_b       = (const float*)d_in[10];
    const float* A_log      = (const float*)d_in[11];
    const float* D_param    = (const float*)d_in[12];
    const float* out_proj_w = (const float*)d_in[13];
    const float* fnorm_w    = (const float*)d_in[14];
    const float* fnorm_b    = (const float*)d_in[15];
    const float* head_w     = (const float*)d_in[16];
    float* out = (float*)d_out;
    float* ws  = (float*)d_ws;

    // fp32 workspace (floats)
    float* h      = ws;                   // B*L*DM    = 2,097,152
    float* xp     = h    + 2097152;       // B*L*XPD   =   327,680
    float* Pc     = xp   + 327680;        // B*NC*N*DI = 2,097,152
    float* Sc     = Pc   + 2097152;       // 2,097,152
    float* part_h = Sc   + 2097152;       // 2 x B*L*DM = 4,194,304
    // bf16 workspace
    __hip_bfloat16* bfb = (__hip_bfloat16*)(part_h + 4194304);
    __hip_bfloat16* xz_b  = bfb;                 // B*L*2DI = 8,388,608 el
    __hip_bfloat16* xln_b = xz_b  + 8388608;     // B*L*DM  = 2,097,152 el
    __hip_bfloat16* y_b   = xln_b + 2097152;     // B*L*DI  = 4,194,304 el
    __hip_bfloat16* xb_b  = y_b   + 4194304;     // B*L*DI  = 4,194,304 el
    __hip_bfloat16* dlt_b = xb_b  + 4194304;     // B*L*DI  = 4,194,304 el
    __hip_bfloat16* xp_b  = dlt_b + 4194304;     // B*L*XPD =   327,680 el
    __hip_bfloat16* dtw_b = xp_b  + 327680;      // NL*DI*DTR = 1,048,576 el
    __hip_bfloat16* ipw_b = dtw_b + 1048576;     // NL*2DI*DM = 16,777,216 el
    __hip_bfloat16* opw_b = ipw_b + 16777216;    // NL*DM*DI  =  8,388,608 el
    __hip_bfloat16* xpw_b = opw_b + 8388608;     // NL*256*2048 = 2,097,152 el
    // split-K partials for xproj alias Pc+Sc (dead until ssm_pass1)
    float* part_xp = Pc;   // 8 x 2048 x 160 = 2,621,440 fl <= 4,194,304 fl

    // ---- weights -> bf16 + embedding + layer-0 LN, one launch
    wconv_embed_k<<<13824 + B_ * L_, 256, 0, stream>>>(
        in_proj_w, out_proj_w, dt_w, xproj_w, ipw_b, opw_b, dtw_b, xpw_b,
        tokens, tok_emb, pos_emb, ln_w, ln_b, h, xln_b);

    for (int li = 0; li < NL_; ++li) {
        // xz = x @ in_proj_w^T  (2048 x 4096, K=1024) -> bf16 [TN=64, 1024 blk]
        gemm_bf16<0, 64><<<dim3(2 * DI_ / 64, B_ * L_ / 128), 256, 0, stream>>>(
            xln_b, DM_, ipw_b + (size_t)li * 2 * DI_ * DM_, DM_,
            xz_b, 2 * DI_, DM_, 0, nullptr);

        // x_branch = silu(conv(xz[...,:DI]))  -> bf16 (8 ch/thread)
        conv_silu<<<B_ * L_ * DI_ / 8 / 256, 256, 0, stream>>>(
            xz_b, conv_w + li * DI_ * K_, conv_b + li * DI_, xb_b);

        // xp = x_branch @ xproj_w^T  (2048 x 160, K=2048) [TN=128 splitK-8]
        gemm_bf16<3, 128><<<dim3(2, B_ * L_ / 128, 8), 256, 0, stream>>>(
            xb_b, DI_, xpw_b + (size_t)li * 256 * 2048, DI_,
            part_xp, XPD_, DI_ / 8, XPD_, nullptr);
        reduce_xp_k<8><<<B_ * L_ * XPD_ / 1024, 256, 0, stream>>>(
            part_xp, xp, xp_b, (size_t)B_ * L_ * XPD_);

        // delta = softplus(dt_r @ dt_w^T + dt_b) (2048x2048, K=128) [TN=64]
        gemm_bf16<5, 64><<<dim3(DI_ / 64, B_ * L_ / 128), 256, 0, stream>>>(
            xp_b, XPD_, dtw_b + (size_t)li * DI_ * DTR_, DTR_,
            dlt_b, DI_, DTR_, 0, dt_b + li * DI_);

        // chunked selective scan
        ssm_pass1<<<B_ * NC_ * (DI_ / 256), 256, 0, stream>>>(
            xb_b, dlt_b, xp, A_log + li * DI_ * N_, Pc, Sc);
        ssm_pass2<<<B_ * NC_ * (DI_ / 256), 256, 0, stream>>>(
            xb_b, dlt_b, xp, A_log + li * DI_ * N_, D_param + li * DI_,
            xz_b, Pc, Sc, y_b);

        // h += y @ out_proj_w^T  (2048 x 1024, K=2048) [TN=64 splitK-2]
        gemm_bf16<2, 64><<<dim3(DM_ / 64, B_ * L_ / 128, 2), 256, 0, stream>>>(
            y_b, DI_, opw_b + (size_t)li * DM_ * DI_, DI_,
            part_h, DM_, DI_ / 2, 0, nullptr);

        if (li < NL_ - 1) {
            reduce_ln_k<2><<<B_ * L_, 256, 0, stream>>>(
                part_h, h, ln_w + (li + 1) * DM_, ln_b + (li + 1) * DM_,
                xln_b, (size_t)B_ * L_ * DM_);
        }
    }

    // fused last-layer residual + final LN + head
    head_ln_k<<<B_ * P_, 256, 0, stream>>>(
        h, part_h, (size_t)B_ * L_ * DM_, fnorm_w, fnorm_b, head_w, out);
}